// Round 1
// 2155.707 us; speedup vs baseline: 1.1125x; 1.1125x over previous
//
#include <hip/hip_runtime.h>
#include <math.h>

typedef unsigned short u16;
typedef u16 ushort8 __attribute__((ext_vector_type(8)));
typedef __bf16 bf16x8 __attribute__((ext_vector_type(8)));
typedef float floatx4 __attribute__((ext_vector_type(4)));

__device__ __forceinline__ float bf2f(u16 u) {
  union { unsigned int i; float f; } v; v.i = ((unsigned int)u) << 16; return v.f;
}
__device__ __forceinline__ u16 f2bf(float f) {
  union { float f; unsigned int i; } v; v.f = f;
  return (u16)((v.i + 0x7fffu + ((v.i >> 16) & 1u)) >> 16);
}

#define CEILDIV(a, b) (((a) + (b) - 1) / (b))

// ---------------- async global->LDS, 16 B per lane ----------------
typedef const __attribute__((address_space(1))) unsigned int ga_u32;
typedef __attribute__((address_space(3))) unsigned int lds_u32;
__device__ __forceinline__ void gload16(const u16* g, u16* l) {
  // LDS dest is wave-uniform base; HW adds lane*16. Global src is per-lane.
  __builtin_amdgcn_global_load_lds((ga_u32*)g, (lds_u32*)l, 16, 0, 0);
}

// ---------------- f32 -> bf16 convert (streaming) ----------------
__global__ void k_cvt(const float* __restrict__ in, u16* __restrict__ out, int n8) {
  int t = blockIdx.x * blockDim.x + threadIdx.x;
  if (t >= n8) return;
  const floatx4* p = (const floatx4*)(in + (size_t)t * 8);
  floatx4 a = p[0], b = p[1];
  u16 o[8];
#pragma unroll
  for (int j = 0; j < 4; j++) { o[j] = f2bf(a[j]); o[4 + j] = f2bf(b[j]); }
  *(ushort8*)(out + (size_t)t * 8) = *(ushort8*)o;
}

// ---------------- transpose+convert: W[K][N] (f32) -> Wt[N][K] (bf16) ----------------
__global__ void k_transpose(const float* __restrict__ W, u16* __restrict__ Wt, int K, int N) {
  int t = blockIdx.x * blockDim.x + threadIdx.x;
  if (t >= K * N) return;
  int n = t / K, k = t - n * K;
  Wt[t] = f2bf(W[k * N + n]);
}

// ---------------- CSR build ----------------
__global__ void k_hist(const int* __restrict__ dst, int E, int* __restrict__ cnt) {
  int t = blockIdx.x * blockDim.x + threadIdx.x;
  if (t < E) atomicAdd(&cnt[dst[t]], 1);
}

__global__ __launch_bounds__(1024) void k_scan(const int* __restrict__ cnt, int* __restrict__ rp, int n) {
  __shared__ int sm[1024];
  int t = threadIdx.x;
  int chunk = (n + 1023) >> 10;
  int s = t * chunk, e = min(n, s + chunk);
  int loc = 0;
  for (int i = s; i < e; ++i) loc += cnt[i];
  sm[t] = loc;
  __syncthreads();
  for (int off = 1; off < 1024; off <<= 1) {
    int v = (t >= off) ? sm[t - off] : 0;
    __syncthreads();
    sm[t] += v;
    __syncthreads();
  }
  int base = sm[t] - loc;
  for (int i = s; i < e; ++i) { rp[i] = base; base += cnt[i]; }
  if (t == 1023) rp[n] = sm[1023];
}

__global__ void k_scatter(const int* __restrict__ dst, int E, const int* __restrict__ rp,
                          int* __restrict__ cur, int* __restrict__ eidx) {
  int t = blockIdx.x * blockDim.x + threadIdx.x;
  if (t >= E) return;
  int d = dst[t];
  int p = atomicAdd(&cur[d], 1);
  eidx[rp[d] + p] = t;
}

// ---------------- GEMM: C[M,N] = A[M,K](bf16) @ Bt[N,K]^T (+bias), fp32 acc ----------------
// m97-style: global_load_lds(16B) direct-to-LDS, double-buffered, ONE barrier per K-step.
// MODE 0: store bf16 Cb. MODE 1: tanh(C+bias) colsum atomic. MODE 2: store f32 Cf.
#define BM 128
#define BN 128
#define BK 32

template <int MODE>
__global__ __launch_bounds__(256) void k_gemm2(
    const u16* __restrict__ A, const u16* __restrict__ Bt, const float* __restrict__ bias,
    u16* __restrict__ Cb, float* __restrict__ Cf, float* __restrict__ colsum,
    int M, int N, int K) {
  __shared__ __align__(16) u16 sm[2][2][BM * BK];  // [dbuf][A|B][128x32] = 32 KiB
  int tid = threadIdx.x;
  int lane = tid & 63, wid = tid >> 6;
  int wm = wid >> 1, wn = wid & 1;
  int quad = lane >> 4, l16 = lane & 15;
  int m0 = blockIdx.x * BM, n0 = blockIdx.y * BN;

  // staging geometry: wave wid owns rows [wid*32, wid*32+32); two 16-row chunks.
  int sr = lane >> 2;           // 0..15: row within chunk
  int sc = (lane & 3) * 8;      // u16 col 0/8/16/24 (16 B granule)
  int ra0 = m0 + wid * 32 + sr;
  int ra1 = ra0 + 16;
  int rb0 = n0 + wid * 32 + sr;
  int rb1 = rb0 + 16;
  // clamp OOB rows to last valid row: garbage rows/cols are computed but never stored
  if (ra0 >= M) ra0 = M - 1;
  if (ra1 >= M) ra1 = M - 1;
  if (rb0 >= N) rb0 = N - 1;
  if (rb1 >= N) rb1 = N - 1;
  const u16* ga0 = A + (size_t)ra0 * K + sc;
  const u16* ga1 = A + (size_t)ra1 * K + sc;
  const u16* gb0 = Bt + (size_t)rb0 * K + sc;
  const u16* gb1 = Bt + (size_t)rb1 * K + sc;
  const int la = wid * 32 * BK;        // u16 index of chunk 0 base (wave-uniform)
  const int lb = la + 16 * BK;         // chunk 1 base

  floatx4 acc[4][4];
#pragma unroll
  for (int i = 0; i < 4; i++)
#pragma unroll
    for (int j = 0; j < 4; j++) acc[i][j] = (floatx4){0.f, 0.f, 0.f, 0.f};

  auto stage = [&](int buf, int k0) {
    u16* sa = &sm[buf][0][0];
    u16* sb = &sm[buf][1][0];
    gload16(ga0 + k0, sa + la);
    gload16(ga1 + k0, sa + lb);
    gload16(gb0 + k0, sb + la);
    gload16(gb1 + k0, sb + lb);
  };

  stage(0, 0);
  __syncthreads();  // compiler drains vmcnt(0) before the barrier

  int nk = K / BK;
  for (int t = 0; t < nk; ++t) {
    int cur = t & 1;
    if (t + 1 < nk) stage(cur ^ 1, (t + 1) * BK);  // issue BEFORE ds_read+MFMA (T3 recipe)
    const u16* Ab = &sm[cur][0][0];
    const u16* Bb = &sm[cur][1][0];
    bf16x8 af[4], bfr[4];
#pragma unroll
    for (int mi = 0; mi < 4; mi++)
      af[mi] = *(const bf16x8*)(Ab + (wm * 64 + mi * 16 + l16) * BK + quad * 8);
#pragma unroll
    for (int ni = 0; ni < 4; ni++)
      bfr[ni] = *(const bf16x8*)(Bb + (wn * 64 + ni * 16 + l16) * BK + quad * 8);
#pragma unroll
    for (int mi = 0; mi < 4; mi++)
#pragma unroll
      for (int ni = 0; ni < 4; ni++)
        acc[mi][ni] = __builtin_amdgcn_mfma_f32_16x16x32_bf16(af[mi], bfr[ni], acc[mi][ni], 0, 0, 0);
    __syncthreads();  // one barrier per K-step: drains the prefetch + protects LDS reuse
  }

  if (MODE == 1) {
#pragma unroll
    for (int ni = 0; ni < 4; ni++) {
      int gc = n0 + wn * 64 + ni * 16 + l16;
      float bv = bias[gc];
      float part = 0.f;
#pragma unroll
      for (int mi = 0; mi < 4; mi++) {
#pragma unroll
        for (int r = 0; r < 4; r++) {
          int gr = m0 + wm * 64 + mi * 16 + quad * 4 + r;
          if (gr < M) part += tanhf(acc[mi][ni][r] + bv);
        }
      }
      part += __shfl_xor(part, 16);
      part += __shfl_xor(part, 32);
      if (lane < 16) atomicAdd(&colsum[gc], part);
    }
  } else if (MODE == 0 && (N & 127) == 0) {
    // LDS transpose epilogue: coalesced 32B/lane row stores
    float* smf = (float*)sm;
    float* tw = smf + wid * 16 * 68;  // per-wave 16x68 f32 region
#pragma unroll
    for (int mi = 0; mi < 4; mi++) {
#pragma unroll
      for (int ni = 0; ni < 4; ni++)
#pragma unroll
        for (int r = 0; r < 4; r++)
          tw[(quad * 4 + r) * 68 + ni * 16 + l16] = acc[mi][ni][r];
      int row = lane >> 2, cq = (lane & 3) * 16;
      int gr = m0 + wm * 64 + mi * 16 + row;
      if (gr < M) {
        int gc0 = n0 + wn * 64 + cq;
        u16 ob[16];
#pragma unroll
        for (int j = 0; j < 16; j++) ob[j] = f2bf(tw[row * 68 + cq + j] + bias[gc0 + j]);
        *(ushort8*)(Cb + (size_t)gr * N + gc0) = *(ushort8*)ob;
        *(ushort8*)(Cb + (size_t)gr * N + gc0 + 8) = *(ushort8*)(ob + 8);
      }
    }
  } else {
#pragma unroll
    for (int ni = 0; ni < 4; ni++) {
      int gc = n0 + wn * 64 + ni * 16 + l16;
      if (gc >= N) continue;
      float bv = bias[gc];
#pragma unroll
      for (int mi = 0; mi < 4; mi++) {
#pragma unroll
        for (int r = 0; r < 4; r++) {
          int gr = m0 + wm * 64 + mi * 16 + quad * 4 + r;
          if (gr < M) {
            float v = acc[mi][ni][r] + bv;
            if (MODE == 0) Cb[(size_t)gr * N + gc] = f2bf(v);
            else Cf[(size_t)gr * N + gc] = v;
          }
        }
      }
    }
  }
}

// ---------------- per-node attention logits ----------------
__global__ void k_logits(const u16* __restrict__ h, int N,
                         const float* __restrict__ a0, const float* __restrict__ a1,
                         const float* __restrict__ a2, const float* __restrict__ a3,
                         float* __restrict__ o0, float* __restrict__ o1,
                         float* __restrict__ o2, float* __restrict__ o3) {
  int t = blockIdx.x * blockDim.x + threadIdx.x;
  int n = t >> 3, hh = t & 7;
  if (n >= N) return;
  const ushort8* hp = (const ushort8*)(h + (size_t)n * 256 + hh * 32);
  float d0 = 0.f, d1 = 0.f, d2 = 0.f, d3 = 0.f;
#pragma unroll
  for (int q = 0; q < 4; q++) {
    ushort8 v = hp[q];
#pragma unroll
    for (int j = 0; j < 8; j++) {
      float f = bf2f(v[j]);
      int idx = hh * 32 + q * 8 + j;
      d0 += f * a0[idx];
      d1 += f * a1[idx];
      if (a2) d2 += f * a2[idx];
      if (a3) d3 += f * a3[idx];
    }
  }
  o0[t] = d0;
  o1[t] = d1;
  if (o2) o2[t] = d2;
  if (o3) o3[t] = d3;
}

// ---------------- fused per-(dst,head) softmax + aggregate, one wave per dst ----------------
__global__ __launch_bounds__(256) void k_attn_agg(
    const int* __restrict__ rp, const int* __restrict__ eidx, const int* __restrict__ src,
    const float* __restrict__ als, const float* __restrict__ ald,
    const u16* __restrict__ hsrc, u16* __restrict__ out, int Ndst) {
  int wid = threadIdx.x >> 6, lane = threadIdx.x & 63;
  int n = blockIdx.x * 4 + wid;
  if (n >= Ndst) return;
  int hh = lane >> 3, sub = lane & 7;
  int b = rp[n], e = rp[n + 1];
  float av = ald[n * 8 + hh];
  float m = -1e30f, s = 0.f;
  {
    int i = b + sub;
    for (; i + 8 < e; i += 16) {
      int e0 = eidx[i], e1 = eidx[i + 8];
      int s0 = src[e0], s1 = src[e1];
      float x0 = als[s0 * 8 + hh] + av, x1 = als[s1 * 8 + hh] + av;
      x0 = x0 > 0.f ? x0 : 0.2f * x0;
      x1 = x1 > 0.f ? x1 : 0.2f * x1;
      float mx = fmaxf(x0, x1);
      float pair = expf(x0 - mx) + expf(x1 - mx);
      if (mx > m) { s = s * expf(m - mx) + pair; m = mx; }
      else s += pair * expf(mx - m);
    }
    if (i < e) {
      int e0 = eidx[i];
      float x0 = als[src[e0] * 8 + hh] + av;
      x0 = x0 > 0.f ? x0 : 0.2f * x0;
      if (x0 > m) { s = s * expf(m - x0) + 1.f; m = x0; }
      else s += expf(x0 - m);
    }
  }
#pragma unroll
  for (int msk = 1; msk < 8; msk <<= 1) {
    float mo = __shfl_xor(m, msk), so = __shfl_xor(s, msk);
    float mn = fmaxf(m, mo);
    s = s * expf(m - mn) + so * expf(mo - mn);
    m = mn;
  }
  float inv = 1.f / (s + 1e-16f);
  float a0 = 0.f, a1 = 0.f, a2 = 0.f, a3 = 0.f;
  int i = b;
  for (; i + 1 < e; i += 2) {
    int e0 = eidx[i], e1 = eidx[i + 1];
    int s0 = src[e0], s1 = src[e1];
    float x0 = als[s0 * 8 + hh] + av, x1 = als[s1 * 8 + hh] + av;
    ushort4 v0 = *(const ushort4*)(hsrc + (size_t)s0 * 256 + lane * 4);
    ushort4 v1 = *(const ushort4*)(hsrc + (size_t)s1 * 256 + lane * 4);
    x0 = x0 > 0.f ? x0 : 0.2f * x0;
    x1 = x1 > 0.f ? x1 : 0.2f * x1;
    float w0 = expf(x0 - m) * inv, w1 = expf(x1 - m) * inv;
    a0 += w0 * bf2f(v0.x) + w1 * bf2f(v1.x);
    a1 += w0 * bf2f(v0.y) + w1 * bf2f(v1.y);
    a2 += w0 * bf2f(v0.z) + w1 * bf2f(v1.z);
    a3 += w0 * bf2f(v0.w) + w1 * bf2f(v1.w);
  }
  if (i < e) {
    int e0 = eidx[i];
    int s0 = src[e0];
    float x0 = als[s0 * 8 + hh] + av;
    ushort4 v0 = *(const ushort4*)(hsrc + (size_t)s0 * 256 + lane * 4);
    x0 = x0 > 0.f ? x0 : 0.2f * x0;
    float w0 = expf(x0 - m) * inv;
    a0 += w0 * bf2f(v0.x);
    a1 += w0 * bf2f(v0.y);
    a2 += w0 * bf2f(v0.z);
    a3 += w0 * bf2f(v0.w);
  }
  ushort4 o;
  o.x = f2bf(a0 > 0.f ? a0 : 0.f);
  o.y = f2bf(a1 > 0.f ? a1 : 0.f);
  o.z = f2bf(a2 > 0.f ? a2 : 0.f);
  o.w = f2bf(a3 > 0.f ? a3 : 0.f);
  *(ushort4*)(out + (size_t)n * 256 + lane * 4) = o;
}

// ---------------- semantic attention scores (K=2) ----------------
__global__ void k_scores(const float* __restrict__ cs0, const float* __restrict__ cs1,
                         const float* __restrict__ q, float invN, float* __restrict__ attn) {
  int lane = threadIdx.x;
  float p0 = 0.f, p1 = 0.f;
  for (int f = lane; f < 256; f += 64) {
    float qv = q[f];
    p0 += qv * cs0[f];
    p1 += qv * cs1[f];
  }
  for (int o = 32; o > 0; o >>= 1) {
    p0 += __shfl_down(p0, o);
    p1 += __shfl_down(p1, o);
  }
  if (lane == 0) {
    float s0 = p0 * invN, s1 = p1 * invN;
    float mx = fmaxf(s0, s1);
    float e0 = expf(s0 - mx), e1 = expf(s1 - mx);
    float den = e0 + e1;
    attn[0] = e0 / den;
    attn[1] = e1 / den;
  }
}

__global__ void k_combine(const u16* __restrict__ x0, const u16* __restrict__ x1,
                          const float* __restrict__ attn, u16* __restrict__ out, int total8) {
  int t = blockIdx.x * blockDim.x + threadIdx.x;
  if (t >= total8) return;
  float a0 = attn[0], a1 = attn[1];
  ushort8 u = ((const ushort8*)x0)[t];
  ushort8 v = ((const ushort8*)x1)[t];
  u16 o[8];
#pragma unroll
  for (int j = 0; j < 8; j++) o[j] = f2bf(a0 * bf2f(u[j]) + a1 * bf2f(v[j]));
  ((ushort8*)out)[t] = *(ushort8*)o;
}

extern "C" void kernel_launch(void* const* d_in, const int* in_sizes, int n_in,
                              void* d_out, int out_size, void* d_ws, size_t ws_size,
                              hipStream_t stream) {
  const int NP = 100000, NA = 50000;
  const int EAP = 300000, EPA = 300000, EPP = 500000;

  const float* xP = (const float*)d_in[0];
  const float* xA = (const float*)d_in[1];
  const int* srcAP = (const int*)d_in[2];
  const int* dstAP = (const int*)d_in[3];
  const int* srcPA = (const int*)d_in[4];
  const int* dstPA = (const int*)d_in[5];
  const int* srcPP = (const int*)d_in[6];
  const int* dstPP = (const int*)d_in[7];
  const float *W_P[2], *b_P[2], *W_A[2], *b_A[2];
  const float *asAP[2], *adAP[2], *asPA[2], *adPA[2], *asPP[2], *adPP[2];
  const float *kW[2], *kb[2], *qv[2];
  for (int l = 0; l < 2; ++l) {
    int base = 8 + l * 13;
    W_P[l] = (const float*)d_in[base + 0];
    b_P[l] = (const float*)d_in[base + 1];
    W_A[l] = (const float*)d_in[base + 2];
    b_A[l] = (const float*)d_in[base + 3];
    asAP[l] = (const float*)d_in[base + 4];
    adAP[l] = (const float*)d_in[base + 5];
    asPA[l] = (const float*)d_in[base + 6];
    adPA[l] = (const float*)d_in[base + 7];
    asPP[l] = (const float*)d_in[base + 8];
    adPP[l] = (const float*)d_in[base + 9];
    kW[l] = (const float*)d_in[base + 10];
    kb[l] = (const float*)d_in[base + 11];
    qv[l] = (const float*)d_in[base + 12];
  }
  const float* linW = (const float*)d_in[34];
  const float* linb = (const float*)d_in[35];

  // ---------------- workspace layout (unchanged footprint, ~178 MB) ----------------
  char* ws = (char*)d_ws;
  size_t off = 0;
  auto alloc = [&](size_t bytes) -> char* {
    char* p = ws + off;
    off += (bytes + 255) & ~(size_t)255;
    return p;
  };
  u16* P1 = (u16*)alloc((size_t)NP * 256 * 2);   // adjacent to P2 (exact multiple of 256 B)
  u16* P2 = (u16*)alloc((size_t)NP * 256 * 2);
  u16* A1 = (u16*)alloc((size_t)NA * 256 * 2);   // adjacent to A2
  u16* A2 = (u16*)alloc((size_t)NA * 256 * 2);
  float* ldAP_P = (float*)alloc((size_t)NP * 8 * 4);
  float* lsPA_P = (float*)alloc((size_t)NP * 8 * 4);
  float* lsPP_P = (float*)alloc((size_t)NP * 8 * 4);
  float* ldPP_P = (float*)alloc((size_t)NP * 8 * 4);
  float* lsAP_A = (float*)alloc((size_t)NA * 8 * 4);
  float* ldPA_A = (float*)alloc((size_t)NA * 8 * 4);
  u16* wtP0 = (u16*)alloc(256 * 512 * 2);
  u16* wtA0 = (u16*)alloc(256 * 256 * 2);
  u16* wtP1 = (u16*)alloc(256 * 256 * 2);
  u16* wtA1 = (u16*)alloc(256 * 256 * 2);
  u16* kwt0 = (u16*)alloc(256 * 256 * 2);
  u16* kwt1 = (u16*)alloc(256 * 256 * 2);
  u16* lwt = (u16*)alloc(32 * 256 * 2);
  int* rpAP = (int*)alloc((NP + 1) * 4);
  int* rpPP = (int*)alloc((NP + 1) * 4);
  int* rpPA = (int*)alloc((NA + 1) * 4);
  int* eiAP = (int*)alloc((size_t)EAP * 4);
  int* eiPP = (int*)alloc((size_t)EPP * 4);
  int* eiPA = (int*)alloc((size_t)EPA * 4);
  size_t zbytes = (size_t)(4 * NP + 2 * NA) * 4 + 4 * 256 * 4;
  char* zblock = alloc(zbytes);
  int* cntAP = (int*)zblock;
  int* cntPP = cntAP + NP;
  int* cntPA = cntPP + NP;
  int* curAP = cntPA + NA;
  int* curPP = curAP + NP;
  int* curPA = curPP + NP;
  float* cs = (float*)(curPA + NA);  // 4 x 256
  float* attnBuf = (float*)alloc(256);

  // Overlay views (no extra workspace):
  u16* XPB = P1;                      // [NP][512] bf16 spans exactly P1|P2 (102.4 MB)
  u16* HP = A1;                       // [NP][256] bf16 spans exactly A1|A2 (51.2 MB)
  u16* XAB = P1;                      // [NA][256] bf16 (25.6 MB), lives after XPB is dead
  u16* hA0 = P2;                      // [NA][256] bf16 = first half of P2
  u16* P2b = P2 + (size_t)NA * 256;   // [NA][256] bf16 = second half of P2 (newA)

  hipMemsetAsync((void*)zblock, 0, zbytes, stream);

  // weight transposes (f32 -> bf16)
  k_transpose<<<CEILDIV(512 * 256, 256), 256, 0, stream>>>(W_P[0], wtP0, 512, 256);
  k_transpose<<<CEILDIV(256 * 256, 256), 256, 0, stream>>>(W_A[0], wtA0, 256, 256);
  k_transpose<<<CEILDIV(256 * 256, 256), 256, 0, stream>>>(W_P[1], wtP1, 256, 256);
  k_transpose<<<CEILDIV(256 * 256, 256), 256, 0, stream>>>(W_A[1], wtA1, 256, 256);
  k_transpose<<<CEILDIV(256 * 256, 256), 256, 0, stream>>>(kW[0], kwt0, 256, 256);
  k_transpose<<<CEILDIV(256 * 256, 256), 256, 0, stream>>>(kW[1], kwt1, 256, 256);
  k_transpose<<<CEILDIV(256 * 32, 256), 256, 0, stream>>>(linW, lwt, 256, 32);

  // CSR build (by dst), shared by both layers
  k_hist<<<CEILDIV(EAP, 256), 256, 0, stream>>>(dstAP, EAP, cntAP);
  k_hist<<<CEILDIV(EPP, 256), 256, 0, stream>>>(dstPP, EPP, cntPP);
  k_hist<<<CEILDIV(EPA, 256), 256, 0, stream>>>(dstPA, EPA, cntPA);
  k_scan<<<1, 1024, 0, stream>>>(cntAP, rpAP, NP);
  k_scan<<<1, 1024, 0, stream>>>(cntPP, rpPP, NP);
  k_scan<<<1, 1024, 0, stream>>>(cntPA, rpPA, NA);
  k_scatter<<<CEILDIV(EAP, 256), 256, 0, stream>>>(dstAP, EAP, rpAP, curAP, eiAP);
  k_scatter<<<CEILDIV(EPP, 256), 256, 0, stream>>>(dstPP, EPP, rpPP, curPP, eiPP);
  k_scatter<<<CEILDIV(EPA, 256), 256, 0, stream>>>(dstPA, EPA, rpPA, curPA, eiPA);

  auto G0 = [&](const u16* A, const u16* Bt, const float* bias, u16* Cb, int M, int N, int K) {
    dim3 g(CEILDIV(M, BM), CEILDIV(N, BN));
    k_gemm2<0><<<g, 256, 0, stream>>>(A, Bt, bias, Cb, nullptr, nullptr, M, N, K);
  };
  auto G1 = [&](const u16* A, const u16* Bt, const float* bias, float* colsum, int M, int N, int K) {
    dim3 g(CEILDIV(M, BM), CEILDIV(N, BN));
    k_gemm2<1><<<g, 256, 0, stream>>>(A, Bt, bias, nullptr, nullptr, colsum, M, N, K);
  };
  auto G2 = [&](const u16* A, const u16* Bt, const float* bias, float* Cf, int M, int N, int K) {
    dim3 g(CEILDIV(M, BM), CEILDIV(N, BN));
    k_gemm2<2><<<g, 256, 0, stream>>>(A, Bt, bias, nullptr, Cf, nullptr, M, N, K);
  };

  // =================== Layer 0 ===================
  // pre-convert inputs to bf16 (streaming, HBM-rate)
  k_cvt<<<CEILDIV(NP * 512 / 8, 256), 256, 0, stream>>>(xP, XPB, NP * 512 / 8);
  G0(XPB, wtP0, b_P[0], HP, NP, 256, 512);   // hP -> HP (=A1|A2); XPB dead after this
  k_cvt<<<CEILDIV(NA * 256 / 8, 256), 256, 0, stream>>>(xA, XAB, NA * 256 / 8);
  G0(XAB, wtA0, b_A[0], hA0, NA, 256, 256);  // hA -> P2 first half; XAB dead after this

  k_logits<<<CEILDIV(NP * 8, 256), 256, 0, stream>>>(
      HP, NP, adAP[0], asPA[0], asPP[0], adPP[0], ldAP_P, lsPA_P, lsPP_P, ldPP_P);
  k_logits<<<CEILDIV(NA * 8, 256), 256, 0, stream>>>(
      hA0, NA, asAP[0], adPA[0], nullptr, nullptr, lsAP_A, ldPA_A, nullptr, nullptr);
  // PP: papers->papers (src hP=HP -> oPP=P1)
  k_attn_agg<<<CEILDIV(NP, 4), 256, 0, stream>>>(rpPP, eiPP, srcPP, lsPP_P, ldPP_P, HP, P1, NP);
  // PA: papers->authors (src hP=HP -> oPA=newA=P2b)
  k_attn_agg<<<CEILDIV(NA, 4), 256, 0, stream>>>(rpPA, eiPA, srcPA, lsPA_P, ldPA_A, HP, P2b, NA);
  // AP: authors->papers (src hA=hA0 -> oAP=HP; hP dead now)
  k_attn_agg<<<CEILDIV(NP, 4), 256, 0, stream>>>(rpAP, eiAP, srcAP, lsAP_A, ldAP_P, hA0, HP, NP);
  // semantic over {oAP=HP, oPP=P1}
  G1(HP, kwt0, kb[0], cs, NP, 256, 256);
  G1(P1, kwt0, kb[0], cs + 256, NP, 256, 256);
  k_scores<<<1, 64, 0, stream>>>(cs, cs + 256, qv[0], 1.0f / NP, attnBuf);
  k_combine<<<CEILDIV(NP * 32, 256), 256, 0, stream>>>(HP, P1, attnBuf, P1, NP * 32);  // newP -> P1

  // =================== Layer 1 ===================
  G0(P1, wtP1, b_P[1], HP, NP, 256, 256);    // hP1 -> HP
  G0(P2b, wtA1, b_A[1], hA0, NA, 256, 256);  // hA1 -> P2 first half (reads second half)
  k_logits<<<CEILDIV(NP * 8, 256), 256, 0, stream>>>(
      HP, NP, adAP[1], asPA[1], asPP[1], adPP[1], ldAP_P, lsPA_P, lsPP_P, ldPP_P);
  k_logits<<<CEILDIV(NA * 8, 256), 256, 0, stream>>>(
      hA0, NA, asAP[1], adPA[1], nullptr, nullptr, lsAP_A, ldPA_A, nullptr, nullptr);
  // PP: src hP1=HP -> oPP1=P1 (newP dead after its GEMM)
  k_attn_agg<<<CEILDIV(NP, 4), 256, 0, stream>>>(rpPP, eiPP, srcPP, lsPP_P, ldPP_P, HP, P1, NP);
  // AP: src hA1=hA0 -> oAP1=HP (hP1 dead now)
  k_attn_agg<<<CEILDIV(NP, 4), 256, 0, stream>>>(rpAP, eiAP, srcAP, lsAP_A, ldAP_P, hA0, HP, NP);
  // semantic over {oAP1=HP, oPP1=P1}
  G1(HP, kwt1, kb[1], cs + 512, NP, 256, 256);
  G1(P1, kwt1, kb[1], cs + 768, NP, 256, 256);
  k_scores<<<1, 64, 0, stream>>>(cs + 512, cs + 768, qv[1], 1.0f / NP, attnBuf + 2);
  k_combine<<<CEILDIV(NP * 32, 256), 256, 0, stream>>>(HP, P1, attnBuf + 2, P1, NP * 32);

  // classifier: d_out = newP @ linW + linb (f32)
  G2(P1, lwt, linb, (float*)d_out, NP, 32, 256);
}

// Round 3
// 1807.367 us; speedup vs baseline: 1.3269x; 1.1927x over previous
//
#include <hip/hip_runtime.h>
#include <math.h>

typedef unsigned short u16;
typedef u16 ushort8 __attribute__((ext_vector_type(8)));
typedef __bf16 bf16x8 __attribute__((ext_vector_type(8)));
typedef float floatx4 __attribute__((ext_vector_type(4)));

__device__ __forceinline__ float bf2f(u16 u) {
  union { unsigned int i; float f; } v; v.i = ((unsigned int)u) << 16; return v.f;
}
__device__ __forceinline__ u16 f2bf(float f) {
  union { float f; unsigned int i; } v; v.f = f;
  return (u16)((v.i + 0x7fffu + ((v.i >> 16) & 1u)) >> 16);
}

#define CEILDIV(a, b) (((a) + (b) - 1) / (b))

// ---------------- async global->LDS, 16 B per lane ----------------
typedef const __attribute__((address_space(1))) unsigned int ga_u32;
typedef __attribute__((address_space(3))) unsigned int lds_u32;
__device__ __forceinline__ void gload16(const u16* g, u16* l) {
  __builtin_amdgcn_global_load_lds((ga_u32*)g, (lds_u32*)l, 16, 0, 0);
}

// ---------------- f32 -> bf16 convert (streaming) ----------------
__global__ void k_cvt(const float* __restrict__ in, u16* __restrict__ out, int n8) {
  int t = blockIdx.x * blockDim.x + threadIdx.x;
  if (t >= n8) return;
  const floatx4* p = (const floatx4*)(in + (size_t)t * 8);
  floatx4 a = p[0], b = p[1];
  u16 o[8];
#pragma unroll
  for (int j = 0; j < 4; j++) { o[j] = f2bf(a[j]); o[4 + j] = f2bf(b[j]); }
  *(ushort8*)(out + (size_t)t * 8) = *(ushort8*)o;
}

// ---------------- transpose+convert: W[K][N] (f32) -> Wt[N][K] (bf16) ----------------
__global__ void k_transpose(const float* __restrict__ W, u16* __restrict__ Wt, int K, int N) {
  int t = blockIdx.x * blockDim.x + threadIdx.x;
  if (t >= K * N) return;
  int n = t / K, k = t - n * K;
  Wt[t] = f2bf(W[k * N + n]);
}

// ---------------- CSR build ----------------
__global__ void k_hist(const int* __restrict__ dst, int E, int* __restrict__ cnt) {
  int t = blockIdx.x * blockDim.x + threadIdx.x;
  if (t < E) atomicAdd(&cnt[dst[t]], 1);
}

// ---- two-level exclusive scan, fused over 3 segments (AP:100k, PP:100k, PA:50k) ----
// seg block counts: 98 / 98 / 49 (1024 elems per block) -> 245 blocks total.
__device__ __forceinline__ void seg_map(int b, int& seg, int& bs, int& n) {
  if (b < 98) { seg = 0; bs = b; n = 100000; }
  else if (b < 196) { seg = 1; bs = b - 98; n = 100000; }
  else { seg = 2; bs = b - 196; n = 50000; }
}

__global__ __launch_bounds__(256) void k_scan_a(
    const int* __restrict__ c0, const int* __restrict__ c1, const int* __restrict__ c2,
    int* __restrict__ bsum) {
  int seg, bs, n;
  seg_map(blockIdx.x, seg, bs, n);
  const int* cnt = seg == 0 ? c0 : (seg == 1 ? c1 : c2);
  int t = threadIdx.x;
  int base = bs * 1024 + t * 4;
  int s = 0;
#pragma unroll
  for (int j = 0; j < 4; j++) { int i = base + j; if (i < n) s += cnt[i]; }
#pragma unroll
  for (int o = 1; o < 64; o <<= 1) s += __shfl_xor(s, o);
  __shared__ int wt[4];
  int lane = t & 63, w = t >> 6;
  if (lane == 0) wt[w] = s;
  __syncthreads();
  if (t == 0) bsum[seg * 256 + bs] = wt[0] + wt[1] + wt[2] + wt[3];
}

__global__ __launch_bounds__(256) void k_scan_b(
    const int* __restrict__ bsum, int* __restrict__ bbase,
    int* __restrict__ rp0, int* __restrict__ rp1, int* __restrict__ rp2) {
  __shared__ int sm[256];
  int t = threadIdx.x;
  for (int seg = 0; seg < 3; ++seg) {
    int nb = (seg == 2) ? 49 : 98;
    int n = (seg == 2) ? 50000 : 100000;
    int v = (t < nb) ? bsum[seg * 256 + t] : 0;
    sm[t] = v;
    __syncthreads();
    for (int o = 1; o < 256; o <<= 1) {
      int u = (t >= o) ? sm[t - o] : 0;
      __syncthreads();
      sm[t] += u;
      __syncthreads();
    }
    if (t < nb) bbase[seg * 256 + t] = sm[t] - v;
    if (t == 255) {
      int* rp = seg == 0 ? rp0 : (seg == 1 ? rp1 : rp2);
      rp[n] = sm[255];
    }
    __syncthreads();
  }
}

__global__ __launch_bounds__(256) void k_scan_c(
    const int* __restrict__ c0, const int* __restrict__ c1, const int* __restrict__ c2,
    const int* __restrict__ bbase,
    int* __restrict__ rp0, int* __restrict__ rp1, int* __restrict__ rp2) {
  int seg, bs, n;
  seg_map(blockIdx.x, seg, bs, n);
  const int* cnt = seg == 0 ? c0 : (seg == 1 ? c1 : c2);
  int* rp = seg == 0 ? rp0 : (seg == 1 ? rp1 : rp2);
  int t = threadIdx.x;
  int base = bs * 1024 + t * 4;
  int c[4];
  int s = 0;
#pragma unroll
  for (int j = 0; j < 4; j++) { int i = base + j; c[j] = (i < n) ? cnt[i] : 0; s += c[j]; }
  int lane = t & 63, w = t >> 6;
  int incl = s;
#pragma unroll
  for (int o = 1; o < 64; o <<= 1) { int u = __shfl_up(incl, o); if (lane >= o) incl += u; }
  __shared__ int wt[4];
  if (lane == 63) wt[w] = incl;
  __syncthreads();
  int wb = 0;
#pragma unroll
  for (int j = 0; j < 4; j++) if (j < w) wb += wt[j];
  int thr = bbase[seg * 256 + bs] + wb + incl - s;
#pragma unroll
  for (int j = 0; j < 4; j++) { int i = base + j; if (i < n) rp[i] = thr; thr += c[j]; }
}

__global__ void k_scatter(const int* __restrict__ dst, int E, const int* __restrict__ rp,
                          int* __restrict__ cur, int* __restrict__ eidx) {
  int t = blockIdx.x * blockDim.x + threadIdx.x;
  if (t >= E) return;
  int d = dst[t];
  int p = atomicAdd(&cur[d], 1);
  eidx[rp[d] + p] = t;
}

// ---------------- GEMM: C[M,N] = A[M,K](bf16) @ Bt[N,K]^T (+bias), fp32 acc ----------------
#define BM 128
#define BN 128
#define BK 32

template <int MODE>
__global__ __launch_bounds__(256) void k_gemm2(
    const u16* __restrict__ A, const u16* __restrict__ Bt, const float* __restrict__ bias,
    u16* __restrict__ Cb, float* __restrict__ Cf, float* __restrict__ colsum,
    int M, int N, int K) {
  __shared__ __align__(16) u16 sm[2][2][BM * BK];  // 32 KiB
  int tid = threadIdx.x;
  int lane = tid & 63, wid = tid >> 6;
  int wm = wid >> 1, wn = wid & 1;
  int quad = lane >> 4, l16 = lane & 15;
  int m0 = blockIdx.x * BM, n0 = blockIdx.y * BN;

  int sr = lane >> 2;
  int sc = (lane & 3) * 8;
  int ra0 = m0 + wid * 32 + sr;
  int ra1 = ra0 + 16;
  int rb0 = n0 + wid * 32 + sr;
  int rb1 = rb0 + 16;
  if (ra0 >= M) ra0 = M - 1;
  if (ra1 >= M) ra1 = M - 1;
  if (rb0 >= N) rb0 = N - 1;
  if (rb1 >= N) rb1 = N - 1;
  const u16* ga0 = A + (size_t)ra0 * K + sc;
  const u16* ga1 = A + (size_t)ra1 * K + sc;
  const u16* gb0 = Bt + (size_t)rb0 * K + sc;
  const u16* gb1 = Bt + (size_t)rb1 * K + sc;
  const int la = wid * 32 * BK;
  const int lb = la + 16 * BK;

  floatx4 acc[4][4];
#pragma unroll
  for (int i = 0; i < 4; i++)
#pragma unroll
    for (int j = 0; j < 4; j++) acc[i][j] = (floatx4){0.f, 0.f, 0.f, 0.f};

  auto stage = [&](int buf, int k0) {
    u16* sa = &sm[buf][0][0];
    u16* sb = &sm[buf][1][0];
    gload16(ga0 + k0, sa + la);
    gload16(ga1 + k0, sa + lb);
    gload16(gb0 + k0, sb + la);
    gload16(gb1 + k0, sb + lb);
  };

  stage(0, 0);
  __syncthreads();

  int nk = K / BK;
  for (int t = 0; t < nk; ++t) {
    int cur = t & 1;
    if (t + 1 < nk) stage(cur ^ 1, (t + 1) * BK);
    const u16* Ab = &sm[cur][0][0];
    const u16* Bb = &sm[cur][1][0];
    bf16x8 af[4], bfr[4];
#pragma unroll
    for (int mi = 0; mi < 4; mi++)
      af[mi] = *(const bf16x8*)(Ab + (wm * 64 + mi * 16 + l16) * BK + quad * 8);
#pragma unroll
    for (int ni = 0; ni < 4; ni++)
      bfr[ni] = *(const bf16x8*)(Bb + (wn * 64 + ni * 16 + l16) * BK + quad * 8);
#pragma unroll
    for (int mi = 0; mi < 4; mi++)
#pragma unroll
      for (int ni = 0; ni < 4; ni++)
        acc[mi][ni] = __builtin_amdgcn_mfma_f32_16x16x32_bf16(af[mi], bfr[ni], acc[mi][ni], 0, 0, 0);
    __syncthreads();
  }

  if (MODE == 1) {
#pragma unroll
    for (int ni = 0; ni < 4; ni++) {
      int gc = n0 + wn * 64 + ni * 16 + l16;
      float bv = bias[gc];
      float part = 0.f;
#pragma unroll
      for (int mi = 0; mi < 4; mi++) {
#pragma unroll
        for (int r = 0; r < 4; r++) {
          int gr = m0 + wm * 64 + mi * 16 + quad * 4 + r;
          if (gr < M) part += tanhf(acc[mi][ni][r] + bv);
        }
      }
      part += __shfl_xor(part, 16);
      part += __shfl_xor(part, 32);
      if (lane < 16) atomicAdd(&colsum[gc], part);
    }
  } else if (MODE == 0 && (N & 127) == 0) {
    float* smf = (float*)sm;
    float* tw = smf + wid * 16 * 68;
#pragma unroll
    for (int mi = 0; mi < 4; mi++) {
#pragma unroll
      for (int ni = 0; ni < 4; ni++)
#pragma unroll
        for (int r = 0; r < 4; r++)
          tw[(quad * 4 + r) * 68 + ni * 16 + l16] = acc[mi][ni][r];
      int row = lane >> 2, cq = (lane & 3) * 16;
      int gr = m0 + wm * 64 + mi * 16 + row;
      if (gr < M) {
        int gc0 = n0 + wn * 64 + cq;
        u16 ob[16];
#pragma unroll
        for (int j = 0; j < 16; j++) ob[j] = f2bf(tw[row * 68 + cq + j] + bias[gc0 + j]);
        *(ushort8*)(Cb + (size_t)gr * N + gc0) = *(ushort8*)ob;
        *(ushort8*)(Cb + (size_t)gr * N + gc0 + 8) = *(ushort8*)(ob + 8);
      }
    }
  } else {
#pragma unroll
    for (int ni = 0; ni < 4; ni++) {
      int gc = n0 + wn * 64 + ni * 16 + l16;
      if (gc >= N) continue;
      float bv = bias[gc];
#pragma unroll
      for (int mi = 0; mi < 4; mi++) {
#pragma unroll
        for (int r = 0; r < 4; r++) {
          int gr = m0 + wm * 64 + mi * 16 + quad * 4 + r;
          if (gr < M) {
            float v = acc[mi][ni][r] + bv;
            if (MODE == 0) Cb[(size_t)gr * N + gc] = f2bf(v);
            else Cf[(size_t)gr * N + gc] = v;
          }
        }
      }
    }
  }
}

// ---------------- per-node attention logits ----------------
__global__ void k_logits(const u16* __restrict__ h, int N,
                         const float* __restrict__ a0, const float* __restrict__ a1,
                         const float* __restrict__ a2, const float* __restrict__ a3,
                         float* __restrict__ o0, float* __restrict__ o1,
                         float* __restrict__ o2, float* __restrict__ o3) {
  int t = blockIdx.x * blockDim.x + threadIdx.x;
  int n = t >> 3, hh = t & 7;
  if (n >= N) return;
  const ushort8* hp = (const ushort8*)(h + (size_t)n * 256 + hh * 32);
  float d0 = 0.f, d1 = 0.f, d2 = 0.f, d3 = 0.f;
#pragma unroll
  for (int q = 0; q < 4; q++) {
    ushort8 v = hp[q];
#pragma unroll
    for (int j = 0; j < 8; j++) {
      float f = bf2f(v[j]);
      int idx = hh * 32 + q * 8 + j;
      d0 += f * a0[idx];
      d1 += f * a1[idx];
      if (a2) d2 += f * a2[idx];
      if (a3) d3 += f * a3[idx];
    }
  }
  o0[t] = d0;
  o1[t] = d1;
  if (o2) o2[t] = d2;
  if (o3) o3[t] = d3;
}

// ---------------- fused per-(dst,head) softmax + aggregate, one wave per dst ----------------
__global__ __launch_bounds__(256) void k_attn_agg(
    const int* __restrict__ rp, const int* __restrict__ eidx, const int* __restrict__ src,
    const float* __restrict__ als, const float* __restrict__ ald,
    const u16* __restrict__ hsrc, u16* __restrict__ out, int Ndst) {
  int wid = threadIdx.x >> 6, lane = threadIdx.x & 63;
  int n = blockIdx.x * 4 + wid;
  if (n >= Ndst) return;
  int hh = lane >> 3, sub = lane & 7;
  int b = rp[n], e = rp[n + 1];
  float av = ald[n * 8 + hh];
  float m = -1e30f, s = 0.f;
  {
    int i = b + sub;
    for (; i + 8 < e; i += 16) {
      int e0 = eidx[i], e1 = eidx[i + 8];
      int s0 = src[e0], s1 = src[e1];
      float x0 = als[s0 * 8 + hh] + av, x1 = als[s1 * 8 + hh] + av;
      x0 = x0 > 0.f ? x0 : 0.2f * x0;
      x1 = x1 > 0.f ? x1 : 0.2f * x1;
      float mx = fmaxf(x0, x1);
      float pair = expf(x0 - mx) + expf(x1 - mx);
      if (mx > m) { s = s * expf(m - mx) + pair; m = mx; }
      else s += pair * expf(mx - m);
    }
    if (i < e) {
      int e0 = eidx[i];
      float x0 = als[src[e0] * 8 + hh] + av;
      x0 = x0 > 0.f ? x0 : 0.2f * x0;
      if (x0 > m) { s = s * expf(m - x0) + 1.f; m = x0; }
      else s += expf(x0 - m);
    }
  }
#pragma unroll
  for (int msk = 1; msk < 8; msk <<= 1) {
    float mo = __shfl_xor(m, msk), so = __shfl_xor(s, msk);
    float mn = fmaxf(m, mo);
    s = s * expf(m - mn) + so * expf(mo - mn);
    m = mn;
  }
  float inv = 1.f / (s + 1e-16f);
  float a0 = 0.f, a1 = 0.f, a2 = 0.f, a3 = 0.f;
  int i = b;
  for (; i + 1 < e; i += 2) {
    int e0 = eidx[i], e1 = eidx[i + 1];
    int s0 = src[e0], s1 = src[e1];
    float x0 = als[s0 * 8 + hh] + av, x1 = als[s1 * 8 + hh] + av;
    ushort4 v0 = *(const ushort4*)(hsrc + (size_t)s0 * 256 + lane * 4);
    ushort4 v1 = *(const ushort4*)(hsrc + (size_t)s1 * 256 + lane * 4);
    x0 = x0 > 0.f ? x0 : 0.2f * x0;
    x1 = x1 > 0.f ? x1 : 0.2f * x1;
    float w0 = expf(x0 - m) * inv, w1 = expf(x1 - m) * inv;
    a0 += w0 * bf2f(v0.x) + w1 * bf2f(v1.x);
    a1 += w0 * bf2f(v0.y) + w1 * bf2f(v1.y);
    a2 += w0 * bf2f(v0.z) + w1 * bf2f(v1.z);
    a3 += w0 * bf2f(v0.w) + w1 * bf2f(v1.w);
  }
  if (i < e) {
    int e0 = eidx[i];
    int s0 = src[e0];
    float x0 = als[s0 * 8 + hh] + av;
    ushort4 v0 = *(const ushort4*)(hsrc + (size_t)s0 * 256 + lane * 4);
    x0 = x0 > 0.f ? x0 : 0.2f * x0;
    float w0 = expf(x0 - m) * inv;
    a0 += w0 * bf2f(v0.x);
    a1 += w0 * bf2f(v0.y);
    a2 += w0 * bf2f(v0.z);
    a3 += w0 * bf2f(v0.w);
  }
  ushort4 o;
  o.x = f2bf(a0 > 0.f ? a0 : 0.f);
  o.y = f2bf(a1 > 0.f ? a1 : 0.f);
  o.z = f2bf(a2 > 0.f ? a2 : 0.f);
  o.w = f2bf(a3 > 0.f ? a3 : 0.f);
  *(ushort4*)(out + (size_t)n * 256 + lane * 4) = o;
}

// ---------------- semantic attention scores (K=2) ----------------
__global__ void k_scores(const float* __restrict__ cs0, const float* __restrict__ cs1,
                         const float* __restrict__ q, float invN, float* __restrict__ attn) {
  int lane = threadIdx.x;
  float p0 = 0.f, p1 = 0.f;
  for (int f = lane; f < 256; f += 64) {
    float qv = q[f];
    p0 += qv * cs0[f];
    p1 += qv * cs1[f];
  }
  for (int o = 32; o > 0; o >>= 1) {
    p0 += __shfl_down(p0, o);
    p1 += __shfl_down(p1, o);
  }
  if (lane == 0) {
    float s0 = p0 * invN, s1 = p1 * invN;
    float mx = fmaxf(s0, s1);
    float e0 = expf(s0 - mx), e1 = expf(s1 - mx);
    float den = e0 + e1;
    attn[0] = e0 / den;
    attn[1] = e1 / den;
  }
}

__global__ void k_combine(const u16* __restrict__ x0, const u16* __restrict__ x1,
                          const float* __restrict__ attn, u16* __restrict__ out, int total8) {
  int t = blockIdx.x * blockDim.x + threadIdx.x;
  if (t >= total8) return;
  float a0 = attn[0], a1 = attn[1];
  ushort8 u = ((const ushort8*)x0)[t];
  ushort8 v = ((const ushort8*)x1)[t];
  u16 o[8];
#pragma unroll
  for (int j = 0; j < 8; j++) o[j] = f2bf(a0 * bf2f(u[j]) + a1 * bf2f(v[j]));
  ((ushort8*)out)[t] = *(ushort8*)o;
}

extern "C" void kernel_launch(void* const* d_in, const int* in_sizes, int n_in,
                              void* d_out, int out_size, void* d_ws, size_t ws_size,
                              hipStream_t stream) {
  const int NP = 100000, NA = 50000;
  const int EAP = 300000, EPA = 300000, EPP = 500000;

  const float* xP = (const float*)d_in[0];
  const float* xA = (const float*)d_in[1];
  const int* srcAP = (const int*)d_in[2];
  const int* dstAP = (const int*)d_in[3];
  const int* srcPA = (const int*)d_in[4];
  const int* dstPA = (const int*)d_in[5];
  const int* srcPP = (const int*)d_in[6];
  const int* dstPP = (const int*)d_in[7];
  const float *W_P[2], *b_P[2], *W_A[2], *b_A[2];
  const float *asAP[2], *adAP[2], *asPA[2], *adPA[2], *asPP[2], *adPP[2];
  const float *kW[2], *kb[2], *qv[2];
  for (int l = 0; l < 2; ++l) {
    int base = 8 + l * 13;
    W_P[l] = (const float*)d_in[base + 0];
    b_P[l] = (const float*)d_in[base + 1];
    W_A[l] = (const float*)d_in[base + 2];
    b_A[l] = (const float*)d_in[base + 3];
    asAP[l] = (const float*)d_in[base + 4];
    adAP[l] = (const float*)d_in[base + 5];
    asPA[l] = (const float*)d_in[base + 6];
    adPA[l] = (const float*)d_in[base + 7];
    asPP[l] = (const float*)d_in[base + 8];
    adPP[l] = (const float*)d_in[base + 9];
    kW[l] = (const float*)d_in[base + 10];
    kb[l] = (const float*)d_in[base + 11];
    qv[l] = (const float*)d_in[base + 12];
  }
  const float* linW = (const float*)d_in[34];
  const float* linb = (const float*)d_in[35];

  // ---------------- workspace layout ----------------
  char* ws = (char*)d_ws;
  size_t off = 0;
  auto alloc = [&](size_t bytes) -> char* {
    char* p = ws + off;
    off += (bytes + 255) & ~(size_t)255;
    return p;
  };
  u16* P1 = (u16*)alloc((size_t)NP * 256 * 2);
  u16* P2 = (u16*)alloc((size_t)NP * 256 * 2);
  u16* A1 = (u16*)alloc((size_t)NA * 256 * 2);
  u16* A2 = (u16*)alloc((size_t)NA * 256 * 2);
  float* ldAP_P = (float*)alloc((size_t)NP * 8 * 4);
  float* lsPA_P = (float*)alloc((size_t)NP * 8 * 4);
  float* lsPP_P = (float*)alloc((size_t)NP * 8 * 4);
  float* ldPP_P = (float*)alloc((size_t)NP * 8 * 4);
  float* lsAP_A = (float*)alloc((size_t)NA * 8 * 4);
  float* ldPA_A = (float*)alloc((size_t)NA * 8 * 4);
  u16* wtP0 = (u16*)alloc(256 * 512 * 2);
  u16* wtA0 = (u16*)alloc(256 * 256 * 2);
  u16* wtP1 = (u16*)alloc(256 * 256 * 2);
  u16* wtA1 = (u16*)alloc(256 * 256 * 2);
  u16* kwt0 = (u16*)alloc(256 * 256 * 2);
  u16* kwt1 = (u16*)alloc(256 * 256 * 2);
  u16* lwt = (u16*)alloc(32 * 256 * 2);
  int* rpAP = (int*)alloc((NP + 1) * 4);
  int* rpPP = (int*)alloc((NP + 1) * 4);
  int* rpPA = (int*)alloc((NA + 1) * 4);
  int* eiAP = (int*)alloc((size_t)EAP * 4);
  int* eiPP = (int*)alloc((size_t)EPP * 4);
  int* eiPA = (int*)alloc((size_t)EPA * 4);
  int* bsum = (int*)alloc(768 * 4);
  int* bbase = (int*)alloc(768 * 4);
  size_t zbytes = (size_t)(4 * NP + 2 * NA) * 4 + 4 * 256 * 4;
  char* zblock = alloc(zbytes);
  int* cntAP = (int*)zblock;
  int* cntPP = cntAP + NP;
  int* cntPA = cntPP + NP;
  int* curAP = cntPA + NA;
  int* curPP = curAP + NP;
  int* curPA = curPP + NP;
  float* cs = (float*)(curPA + NA);  // 4 x 256
  float* attnBuf = (float*)alloc(256);

  // Overlay views (no extra workspace):
  u16* XPB = P1;                      // [NP][512] bf16 spans exactly P1|P2
  u16* HP = A1;                       // [NP][256] bf16 spans exactly A1|A2
  u16* XAB = P1;                      // [NA][256] bf16, lives after XPB is dead
  u16* hA0 = P2;                      // [NA][256] bf16 = first half of P2
  u16* P2b = P2 + (size_t)NA * 256;   // [NA][256] bf16 = second half of P2 (newA)

  hipMemsetAsync((void*)zblock, 0, zbytes, stream);

  // weight transposes (f32 -> bf16)
  k_transpose<<<CEILDIV(512 * 256, 256), 256, 0, stream>>>(W_P[0], wtP0, 512, 256);
  k_transpose<<<CEILDIV(256 * 256, 256), 256, 0, stream>>>(W_A[0], wtA0, 256, 256);
  k_transpose<<<CEILDIV(256 * 256, 256), 256, 0, stream>>>(W_P[1], wtP1, 256, 256);
  k_transpose<<<CEILDIV(256 * 256, 256), 256, 0, stream>>>(W_A[1], wtA1, 256, 256);
  k_transpose<<<CEILDIV(256 * 256, 256), 256, 0, stream>>>(kW[0], kwt0, 256, 256);
  k_transpose<<<CEILDIV(256 * 256, 256), 256, 0, stream>>>(kW[1], kwt1, 256, 256);
  k_transpose<<<CEILDIV(256 * 32, 256), 256, 0, stream>>>(linW, lwt, 256, 32);

  // CSR build (by dst), shared by both layers
  k_hist<<<CEILDIV(EAP, 256), 256, 0, stream>>>(dstAP, EAP, cntAP);
  k_hist<<<CEILDIV(EPP, 256), 256, 0, stream>>>(dstPP, EPP, cntPP);
  k_hist<<<CEILDIV(EPA, 256), 256, 0, stream>>>(dstPA, EPA, cntPA);
  k_scan_a<<<245, 256, 0, stream>>>(cntAP, cntPP, cntPA, bsum);
  k_scan_b<<<1, 256, 0, stream>>>(bsum, bbase, rpAP, rpPP, rpPA);
  k_scan_c<<<245, 256, 0, stream>>>(cntAP, cntPP, cntPA, bbase, rpAP, rpPP, rpPA);
  k_scatter<<<CEILDIV(EAP, 256), 256, 0, stream>>>(dstAP, EAP, rpAP, curAP, eiAP);
  k_scatter<<<CEILDIV(EPP, 256), 256, 0, stream>>>(dstPP, EPP, rpPP, curPP, eiPP);
  k_scatter<<<CEILDIV(EPA, 256), 256, 0, stream>>>(dstPA, EPA, rpPA, curPA, eiPA);

  auto G0 = [&](const u16* A, const u16* Bt, const float* bias, u16* Cb, int M, int N, int K) {
    dim3 g(CEILDIV(M, BM), CEILDIV(N, BN));
    k_gemm2<0><<<g, 256, 0, stream>>>(A, Bt, bias, Cb, nullptr, nullptr, M, N, K);
  };
  auto G1 = [&](const u16* A, const u16* Bt, const float* bias, float* colsum, int M, int N, int K) {
    dim3 g(CEILDIV(M, BM), CEILDIV(N, BN));
    k_gemm2<1><<<g, 256, 0, stream>>>(A, Bt, bias, nullptr, nullptr, colsum, M, N, K);
  };
  auto G2 = [&](const u16* A, const u16* Bt, const float* bias, float* Cf, int M, int N, int K) {
    dim3 g(CEILDIV(M, BM), CEILDIV(N, BN));
    k_gemm2<2><<<g, 256, 0, stream>>>(A, Bt, bias, nullptr, Cf, nullptr, M, N, K);
  };

  // =================== Layer 0 ===================
  k_cvt<<<CEILDIV(NP * 512 / 8, 256), 256, 0, stream>>>(xP, XPB, NP * 512 / 8);
  G0(XPB, wtP0, b_P[0], HP, NP, 256, 512);   // hP -> HP (=A1|A2); XPB dead after this
  k_cvt<<<CEILDIV(NA * 256 / 8, 256), 256, 0, stream>>>(xA, XAB, NA * 256 / 8);
  G0(XAB, wtA0, b_A[0], hA0, NA, 256, 256);  // hA -> P2 first half; XAB dead after this

  k_logits<<<CEILDIV(NP * 8, 256), 256, 0, stream>>>(
      HP, NP, adAP[0], asPA[0], asPP[0], adPP[0], ldAP_P, lsPA_P, lsPP_P, ldPP_P);
  k_logits<<<CEILDIV(NA * 8, 256), 256, 0, stream>>>(
      hA0, NA, asAP[0], adPA[0], nullptr, nullptr, lsAP_A, ldPA_A, nullptr, nullptr);
  // PP: papers->papers (src hP=HP -> oPP=P1)
  k_attn_agg<<<CEILDIV(NP, 4), 256, 0, stream>>>(rpPP, eiPP, srcPP, lsPP_P, ldPP_P, HP, P1, NP);
  // PA: papers->authors (src hP=HP -> oPA=newA=P2b)
  k_attn_agg<<<CEILDIV(NA, 4), 256, 0, stream>>>(rpPA, eiPA, srcPA, lsPA_P, ldPA_A, HP, P2b, NA);
  // AP: authors->papers (src hA=hA0 -> oAP=HP; hP dead now)
  k_attn_agg<<<CEILDIV(NP, 4), 256, 0, stream>>>(rpAP, eiAP, srcAP, lsAP_A, ldAP_P, hA0, HP, NP);
  // semantic over {oAP=HP, oPP=P1}
  G1(HP, kwt0, kb[0], cs, NP, 256, 256);
  G1(P1, kwt0, kb[0], cs + 256, NP, 256, 256);
  k_scores<<<1, 64, 0, stream>>>(cs, cs + 256, qv[0], 1.0f / NP, attnBuf);
  k_combine<<<CEILDIV(NP * 32, 256), 256, 0, stream>>>(HP, P1, attnBuf, P1, NP * 32);  // newP -> P1

  // =================== Layer 1 ===================
  G0(P1, wtP1, b_P[1], HP, NP, 256, 256);    // hP1 -> HP
  G0(P2b, wtA1, b_A[1], hA0, NA, 256, 256);  // hA1 -> P2 first half
  k_logits<<<CEILDIV(NP * 8, 256), 256, 0, stream>>>(
      HP, NP, adAP[1], asPA[1], asPP[1], adPP[1], ldAP_P, lsPA_P, lsPP_P, ldPP_P);
  k_logits<<<CEILDIV(NA * 8, 256), 256, 0, stream>>>(
      hA0, NA, asAP[1], adPA[1], nullptr, nullptr, lsAP_A, ldPA_A, nullptr, nullptr);
  // PP: src hP1=HP -> oPP1=P1
  k_attn_agg<<<CEILDIV(NP, 4), 256, 0, stream>>>(rpPP, eiPP, srcPP, lsPP_P, ldPP_P, HP, P1, NP);
  // AP: src hA1=hA0 -> oAP1=HP
  k_attn_agg<<<CEILDIV(NP, 4), 256, 0, stream>>>(rpAP, eiAP, srcAP, lsAP_A, ldAP_P, hA0, HP, NP);
  // semantic over {oAP1=HP, oPP1=P1}
  G1(HP, kwt1, kb[1], cs + 512, NP, 256, 256);
  G1(P1, kwt1, kb[1], cs + 768, NP, 256, 256);
  k_scores<<<1, 64, 0, stream>>>(cs + 512, cs + 768, qv[1], 1.0f / NP, attnBuf + 2);
  k_combine<<<CEILDIV(NP * 32, 256), 256, 0, stream>>>(HP, P1, attnBuf + 2, P1, NP * 32);

  // classifier: d_out = newP @ linW + linb (f32)
  G2(P1, lwt, linb, (float*)d_out, NP, 32, 256);
}

// Round 5
// 1644.025 us; speedup vs baseline: 1.4587x; 1.0994x over previous
//
#include <hip/hip_runtime.h>
#include <math.h>

typedef unsigned short u16;
typedef u16 ushort8 __attribute__((ext_vector_type(8)));
typedef __bf16 bf16x8 __attribute__((ext_vector_type(8)));
typedef float floatx4 __attribute__((ext_vector_type(4)));

__device__ __forceinline__ float bf2f(u16 u) {
  union { unsigned int i; float f; } v; v.i = ((unsigned int)u) << 16; return v.f;
}
__device__ __forceinline__ u16 f2bf(float f) {
  union { float f; unsigned int i; } v; v.f = f;
  return (u16)((v.i + 0x7fffu + ((v.i >> 16) & 1u)) >> 16);
}

#define CEILDIV(a, b) (((a) + (b) - 1) / (b))

// ---------------- async global->LDS, 16 B per lane ----------------
typedef const __attribute__((address_space(1))) unsigned int ga_u32;
typedef __attribute__((address_space(3))) unsigned int lds_u32;
__device__ __forceinline__ void gload16(const u16* g, u16* l) {
  __builtin_amdgcn_global_load_lds((ga_u32*)g, (lds_u32*)l, 16, 0, 0);
}

// ---------------- f32 -> bf16 convert (streaming) ----------------
__global__ void k_cvt(const float* __restrict__ in, u16* __restrict__ out, int n8) {
  int t = blockIdx.x * blockDim.x + threadIdx.x;
  if (t >= n8) return;
  const floatx4* p = (const floatx4*)(in + (size_t)t * 8);
  floatx4 a = p[0], b = p[1];
  u16 o[8];
#pragma unroll
  for (int j = 0; j < 4; j++) { o[j] = f2bf(a[j]); o[4 + j] = f2bf(b[j]); }
  *(ushort8*)(out + (size_t)t * 8) = *(ushort8*)o;
}

// ---------------- transpose+convert: W[K][N] (f32) -> Wt[N][K] (bf16) ----------------
__global__ void k_transpose(const float* __restrict__ W, u16* __restrict__ Wt, int K, int N) {
  int t = blockIdx.x * blockDim.x + threadIdx.x;
  if (t >= K * N) return;
  int n = t / K, k = t - n * K;
  Wt[t] = f2bf(W[k * N + n]);
}

// ---------------- CSR build ----------------
__global__ void k_hist(const int* __restrict__ dst, int E, int* __restrict__ cnt) {
  int t = blockIdx.x * blockDim.x + threadIdx.x;
  if (t < E) atomicAdd(&cnt[dst[t]], 1);
}

// ---- two-level exclusive scan, fused over 3 segments (AP:100k, PP:100k, PA:50k) ----
__device__ __forceinline__ void seg_map(int b, int& seg, int& bs, int& n) {
  if (b < 98) { seg = 0; bs = b; n = 100000; }
  else if (b < 196) { seg = 1; bs = b - 98; n = 100000; }
  else { seg = 2; bs = b - 196; n = 50000; }
}

__global__ __launch_bounds__(256) void k_scan_a(
    const int* __restrict__ c0, const int* __restrict__ c1, const int* __restrict__ c2,
    int* __restrict__ bsum) {
  int seg, bs, n;
  seg_map(blockIdx.x, seg, bs, n);
  const int* cnt = seg == 0 ? c0 : (seg == 1 ? c1 : c2);
  int t = threadIdx.x;
  int base = bs * 1024 + t * 4;
  int s = 0;
#pragma unroll
  for (int j = 0; j < 4; j++) { int i = base + j; if (i < n) s += cnt[i]; }
#pragma unroll
  for (int o = 1; o < 64; o <<= 1) s += __shfl_xor(s, o);
  __shared__ int wt[4];
  int lane = t & 63, w = t >> 6;
  if (lane == 0) wt[w] = s;
  __syncthreads();
  if (t == 0) bsum[seg * 256 + bs] = wt[0] + wt[1] + wt[2] + wt[3];
}

__global__ __launch_bounds__(256) void k_scan_b(
    const int* __restrict__ bsum, int* __restrict__ bbase,
    int* __restrict__ rp0, int* __restrict__ rp1, int* __restrict__ rp2) {
  __shared__ int sm[256];
  int t = threadIdx.x;
  for (int seg = 0; seg < 3; ++seg) {
    int nb = (seg == 2) ? 49 : 98;
    int n = (seg == 2) ? 50000 : 100000;
    int v = (t < nb) ? bsum[seg * 256 + t] : 0;
    sm[t] = v;
    __syncthreads();
    for (int o = 1; o < 256; o <<= 1) {
      int u = (t >= o) ? sm[t - o] : 0;
      __syncthreads();
      sm[t] += u;
      __syncthreads();
    }
    if (t < nb) bbase[seg * 256 + t] = sm[t] - v;
    if (t == 255) {
      int* rp = seg == 0 ? rp0 : (seg == 1 ? rp1 : rp2);
      rp[n] = sm[255];
    }
    __syncthreads();
  }
}

__global__ __launch_bounds__(256) void k_scan_c(
    const int* __restrict__ c0, const int* __restrict__ c1, const int* __restrict__ c2,
    const int* __restrict__ bbase,
    int* __restrict__ rp0, int* __restrict__ rp1, int* __restrict__ rp2) {
  int seg, bs, n;
  seg_map(blockIdx.x, seg, bs, n);
  const int* cnt = seg == 0 ? c0 : (seg == 1 ? c1 : c2);
  int* rp = seg == 0 ? rp0 : (seg == 1 ? rp1 : rp2);
  int t = threadIdx.x;
  int base = bs * 1024 + t * 4;
  int c[4];
  int s = 0;
#pragma unroll
  for (int j = 0; j < 4; j++) { int i = base + j; c[j] = (i < n) ? cnt[i] : 0; s += c[j]; }
  int lane = t & 63, w = t >> 6;
  int incl = s;
#pragma unroll
  for (int o = 1; o < 64; o <<= 1) { int u = __shfl_up(incl, o); if (lane >= o) incl += u; }
  __shared__ int wt[4];
  if (lane == 63) wt[w] = incl;
  __syncthreads();
  int wb = 0;
#pragma unroll
  for (int j = 0; j < 4; j++) if (j < w) wb += wt[j];
  int thr = bbase[seg * 256 + bs] + wb + incl - s;
#pragma unroll
  for (int j = 0; j < 4; j++) { int i = base + j; if (i < n) rp[i] = thr; thr += c[j]; }
}

// scatter stores SRC NODE directly (not edge id): kills one indirection in attn
__global__ void k_scatter(const int* __restrict__ dst, const int* __restrict__ src, int E,
                          const int* __restrict__ rp, int* __restrict__ cur,
                          int* __restrict__ esrc) {
  int t = blockIdx.x * blockDim.x + threadIdx.x;
  if (t >= E) return;
  int d = dst[t];
  int p = atomicAdd(&cur[d], 1);
  esrc[rp[d] + p] = src[t];
}

// ---------------- GEMM: C[M,N] = A[M,K](bf16) @ Bt[N,K]^T (+bias), fp32 acc ----------------
// SRC 0: A via global_load_lds. SRC 1: dual-A reg-staged blend a0*A + a1*A2 (attn scalars).
// MODE 0: store bf16 Cb. MODE 1: fast-tanh(C+bias) colsum atomic. MODE 2: store f32 Cf.
#define BM 128
#define BN 128
#define BK 32

template <int SRC, int MODE>
__global__ __launch_bounds__(256) void k_gemm2(
    const u16* __restrict__ A, const u16* __restrict__ A2, const float* __restrict__ attn,
    const u16* __restrict__ Bt, const float* __restrict__ bias,
    u16* __restrict__ Cb, float* __restrict__ Cf, float* __restrict__ colsum,
    int M, int N, int K) {
  __shared__ __align__(16) u16 sm[2][2][BM * BK];  // 32 KiB
  int tid = threadIdx.x;
  int lane = tid & 63, wid = tid >> 6;
  int wm = wid >> 1, wn = wid & 1;
  int quad = lane >> 4, l16 = lane & 15;
  int m0 = blockIdx.x * BM, n0 = blockIdx.y * BN;

  float a0s = 0.f, a1s = 0.f;
  if (SRC == 1) { a0s = attn[0]; a1s = attn[1]; }

  int sr = lane >> 2;
  int sc = (lane & 3) * 8;
  int ra0 = m0 + wid * 32 + sr;
  int ra1 = ra0 + 16;
  int rb0 = n0 + wid * 32 + sr;
  int rb1 = rb0 + 16;
  if (ra0 >= M) ra0 = M - 1;
  if (ra1 >= M) ra1 = M - 1;
  if (rb0 >= N) rb0 = N - 1;
  if (rb1 >= N) rb1 = N - 1;
  const u16* ga0 = A + (size_t)ra0 * K + sc;
  const u16* ga1 = A + (size_t)ra1 * K + sc;
  const u16* g2a0 = SRC == 1 ? A2 + (size_t)ra0 * K + sc : nullptr;
  const u16* g2a1 = SRC == 1 ? A2 + (size_t)ra1 * K + sc : nullptr;
  const u16* gb0 = Bt + (size_t)rb0 * K + sc;
  const u16* gb1 = Bt + (size_t)rb1 * K + sc;
  const int la = wid * 32 * BK;
  const int lb = la + 16 * BK;

  floatx4 acc[4][4];
#pragma unroll
  for (int i = 0; i < 4; i++)
#pragma unroll
    for (int j = 0; j < 4; j++) acc[i][j] = (floatx4){0.f, 0.f, 0.f, 0.f};

  auto stage = [&](int buf, int k0) {
    u16* sa = &sm[buf][0][0];
    u16* sb = &sm[buf][1][0];
    if (SRC == 0) {
      gload16(ga0 + k0, sa + la);
      gload16(ga1 + k0, sa + lb);
    } else {
      ushort8 u0 = *(const ushort8*)(ga0 + k0);
      ushort8 w0 = *(const ushort8*)(g2a0 + k0);
      ushort8 u1 = *(const ushort8*)(ga1 + k0);
      ushort8 w1 = *(const ushort8*)(g2a1 + k0);
      u16 t0[8], t1[8];
#pragma unroll
      for (int j = 0; j < 8; j++) {
        t0[j] = f2bf(a0s * bf2f(u0[j]) + a1s * bf2f(w0[j]));
        t1[j] = f2bf(a0s * bf2f(u1[j]) + a1s * bf2f(w1[j]));
      }
      *(ushort8*)(sa + la + lane * 8) = *(ushort8*)t0;
      *(ushort8*)(sa + lb + lane * 8) = *(ushort8*)t1;
    }
    gload16(gb0 + k0, sb + la);
    gload16(gb1 + k0, sb + lb);
  };

  stage(0, 0);
  __syncthreads();

  int nk = K / BK;
  for (int t = 0; t < nk; ++t) {
    int cur = t & 1;
    if (t + 1 < nk) stage(cur ^ 1, (t + 1) * BK);
    const u16* Ab = &sm[cur][0][0];
    const u16* Bb = &sm[cur][1][0];
    bf16x8 af[4], bfr[4];
#pragma unroll
    for (int mi = 0; mi < 4; mi++)
      af[mi] = *(const bf16x8*)(Ab + (wm * 64 + mi * 16 + l16) * BK + quad * 8);
#pragma unroll
    for (int ni = 0; ni < 4; ni++)
      bfr[ni] = *(const bf16x8*)(Bb + (wn * 64 + ni * 16 + l16) * BK + quad * 8);
#pragma unroll
    for (int mi = 0; mi < 4; mi++)
#pragma unroll
      for (int ni = 0; ni < 4; ni++)
        acc[mi][ni] = __builtin_amdgcn_mfma_f32_16x16x32_bf16(af[mi], bfr[ni], acc[mi][ni], 0, 0, 0);
    __syncthreads();
  }

  if (MODE == 1) {
#pragma unroll
    for (int ni = 0; ni < 4; ni++) {
      int gc = n0 + wn * 64 + ni * 16 + l16;
      float bv = bias[gc];
      float part = 0.f;
#pragma unroll
      for (int mi = 0; mi < 4; mi++) {
#pragma unroll
        for (int r = 0; r < 4; r++) {
          int gr = m0 + wm * 64 + mi * 16 + quad * 4 + r;
          if (gr < M) {
            float v = acc[mi][ni][r] + bv;
            // fast tanh: 1 - 2/(e^{2v}+1)   (inf-safe: e2=inf -> 1; e2=0 -> -1)
            float e2 = __expf(2.f * v);
            part += 1.f - 2.f / (e2 + 1.f);
          }
        }
      }
      part += __shfl_xor(part, 16);
      part += __shfl_xor(part, 32);
      if (lane < 16) atomicAdd(&colsum[gc], part);
    }
  } else if (MODE == 0 && (N & 127) == 0) {
    float* smf = (float*)sm;
    float* tw = smf + wid * 16 * 68;
#pragma unroll
    for (int mi = 0; mi < 4; mi++) {
#pragma unroll
      for (int ni = 0; ni < 4; ni++)
#pragma unroll
        for (int r = 0; r < 4; r++)
          tw[(quad * 4 + r) * 68 + ni * 16 + l16] = acc[mi][ni][r];
      int row = lane >> 2, cq = (lane & 3) * 16;
      int gr = m0 + wm * 64 + mi * 16 + row;
      if (gr < M) {
        int gc0 = n0 + wn * 64 + cq;
        u16 ob[16];
#pragma unroll
        for (int j = 0; j < 16; j++) ob[j] = f2bf(tw[row * 68 + cq + j] + bias[gc0 + j]);
        *(ushort8*)(Cb + (size_t)gr * N + gc0) = *(ushort8*)ob;
        *(ushort8*)(Cb + (size_t)gr * N + gc0 + 8) = *(ushort8*)(ob + 8);
      }
    }
  } else {
#pragma unroll
    for (int ni = 0; ni < 4; ni++) {
      int gc = n0 + wn * 64 + ni * 16 + l16;
      if (gc >= N) continue;
      float bv = bias[gc];
#pragma unroll
      for (int mi = 0; mi < 4; mi++) {
#pragma unroll
        for (int r = 0; r < 4; r++) {
          int gr = m0 + wm * 64 + mi * 16 + quad * 4 + r;
          if (gr < M) {
            float v = acc[mi][ni][r] + bv;
            if (MODE == 0) Cb[(size_t)gr * N + gc] = f2bf(v);
            else Cf[(size_t)gr * N + gc] = v;
          }
        }
      }
    }
  }
}

// ---------------- per-node attention logits ----------------
__global__ void k_logits(const u16* __restrict__ h, int N,
                         const float* __restrict__ a0, const float* __restrict__ a1,
                         const float* __restrict__ a2, const float* __restrict__ a3,
                         float* __restrict__ o0, float* __restrict__ o1,
                         float* __restrict__ o2, float* __restrict__ o3) {
  int t = blockIdx.x * blockDim.x + threadIdx.x;
  int n = t >> 3, hh = t & 7;
  if (n >= N) return;
  const ushort8* hp = (const ushort8*)(h + (size_t)n * 256 + hh * 32);
  float d0 = 0.f, d1 = 0.f, d2 = 0.f, d3 = 0.f;
#pragma unroll
  for (int q = 0; q < 4; q++) {
    ushort8 v = hp[q];
#pragma unroll
    for (int j = 0; j < 8; j++) {
      float f = bf2f(v[j]);
      int idx = hh * 32 + q * 8 + j;
      d0 += f * a0[idx];
      d1 += f * a1[idx];
      if (a2) d2 += f * a2[idx];
      if (a3) d3 += f * a3[idx];
    }
  }
  o0[t] = d0;
  o1[t] = d1;
  if (o2) o2[t] = d2;
  if (o3) o3[t] = d3;
}

// ---------------- fused softmax + aggregate: SINGLE-PASS online, one wave per dst ----------------
__global__ __launch_bounds__(256) void k_attn_agg(
    const int* __restrict__ rp, const int* __restrict__ esrc,
    const float* __restrict__ als, const float* __restrict__ ald,
    const u16* __restrict__ hsrc, u16* __restrict__ out, int Ndst) {
  int wid = threadIdx.x >> 6, lane = threadIdx.x & 63;
  int n = blockIdx.x * 4 + wid;
  if (n >= Ndst) return;
  int hh = lane >> 3;
  int b = rp[n], e = rp[n + 1];
  float av = ald[n * 8 + hh];
  float m = -1e30f, s = 0.f;
  float a0 = 0.f, a1 = 0.f, a2 = 0.f, a3 = 0.f;
  int i = b;
  for (; i + 1 < e; i += 2) {
    int s0 = esrc[i], s1 = esrc[i + 1];
    float x0 = als[s0 * 8 + hh] + av, x1 = als[s1 * 8 + hh] + av;
    ushort4 v0 = *(const ushort4*)(hsrc + (size_t)s0 * 256 + lane * 4);
    ushort4 v1 = *(const ushort4*)(hsrc + (size_t)s1 * 256 + lane * 4);
    x0 = x0 > 0.f ? x0 : 0.2f * x0;
    x1 = x1 > 0.f ? x1 : 0.2f * x1;
    float mx = fmaxf(x0, x1);
    if (mx > m) {
      float r = __expf(m - mx);
      s *= r; a0 *= r; a1 *= r; a2 *= r; a3 *= r;
      m = mx;
    }
    float w0 = __expf(x0 - m), w1 = __expf(x1 - m);
    s += w0 + w1;
    a0 += w0 * bf2f(v0.x) + w1 * bf2f(v1.x);
    a1 += w0 * bf2f(v0.y) + w1 * bf2f(v1.y);
    a2 += w0 * bf2f(v0.z) + w1 * bf2f(v1.z);
    a3 += w0 * bf2f(v0.w) + w1 * bf2f(v1.w);
  }
  if (i < e) {
    int s0 = esrc[i];
    float x0 = als[s0 * 8 + hh] + av;
    ushort4 v0 = *(const ushort4*)(hsrc + (size_t)s0 * 256 + lane * 4);
    x0 = x0 > 0.f ? x0 : 0.2f * x0;
    if (x0 > m) {
      float r = __expf(m - x0);
      s *= r; a0 *= r; a1 *= r; a2 *= r; a3 *= r;
      m = x0;
    }
    float w0 = __expf(x0 - m);
    s += w0;
    a0 += w0 * bf2f(v0.x);
    a1 += w0 * bf2f(v0.y);
    a2 += w0 * bf2f(v0.z);
    a3 += w0 * bf2f(v0.w);
  }
  float inv = 1.f / (s + 1e-16f);
  a0 *= inv; a1 *= inv; a2 *= inv; a3 *= inv;
  ushort4 o;
  o.x = f2bf(a0 > 0.f ? a0 : 0.f);
  o.y = f2bf(a1 > 0.f ? a1 : 0.f);
  o.z = f2bf(a2 > 0.f ? a2 : 0.f);
  o.w = f2bf(a3 > 0.f ? a3 : 0.f);
  *(ushort4*)(out + (size_t)n * 256 + lane * 4) = o;
}

// ---------------- semantic attention scores (K=2) ----------------
__global__ void k_scores(const float* __restrict__ cs0, const float* __restrict__ cs1,
                         const float* __restrict__ q, float invN, float* __restrict__ attn) {
  int lane = threadIdx.x;
  float p0 = 0.f, p1 = 0.f;
  for (int f = lane; f < 256; f += 64) {
    float qv = q[f];
    p0 += qv * cs0[f];
    p1 += qv * cs1[f];
  }
  for (int o = 32; o > 0; o >>= 1) {
    p0 += __shfl_down(p0, o);
    p1 += __shfl_down(p1, o);
  }
  if (lane == 0) {
    float s0 = p0 * invN, s1 = p1 * invN;
    float mx = fmaxf(s0, s1);
    float e0 = __expf(s0 - mx), e1 = __expf(s1 - mx);
    float den = e0 + e1;
    attn[0] = e0 / den;
    attn[1] = e1 / den;
  }
}

extern "C" void kernel_launch(void* const* d_in, const int* in_sizes, int n_in,
                              void* d_out, int out_size, void* d_ws, size_t ws_size,
                              hipStream_t stream) {
  const int NP = 100000, NA = 50000;
  const int EAP = 300000, EPA = 300000, EPP = 500000;

  const float* xP = (const float*)d_in[0];
  const float* xA = (const float*)d_in[1];
  const int* srcAP = (const int*)d_in[2];
  const int* dstAP = (const int*)d_in[3];
  const int* srcPA = (const int*)d_in[4];
  const int* dstPA = (const int*)d_in[5];
  const int* srcPP = (const int*)d_in[6];
  const int* dstPP = (const int*)d_in[7];
  const float *W_P[2], *b_P[2], *W_A[2], *b_A[2];
  const float *asAP[2], *adAP[2], *asPA[2], *adPA[2], *asPP[2], *adPP[2];
  const float *kW[2], *kb[2], *qv[2];
  for (int l = 0; l < 2; ++l) {
    int base = 8 + l * 13;
    W_P[l] = (const float*)d_in[base + 0];
    b_P[l] = (const float*)d_in[base + 1];
    W_A[l] = (const float*)d_in[base + 2];
    b_A[l] = (const float*)d_in[base + 3];
    asAP[l] = (const float*)d_in[base + 4];
    adAP[l] = (const float*)d_in[base + 5];
    asPA[l] = (const float*)d_in[base + 6];
    adPA[l] = (const float*)d_in[base + 7];
    asPP[l] = (const float*)d_in[base + 8];
    adPP[l] = (const float*)d_in[base + 9];
    kW[l] = (const float*)d_in[base + 10];
    kb[l] = (const float*)d_in[base + 11];
    qv[l] = (const float*)d_in[base + 12];
  }
  const float* linW = (const float*)d_in[34];
  const float* linb = (const float*)d_in[35];

  // ---------------- workspace layout ----------------
  char* ws = (char*)d_ws;
  size_t off = 0;
  auto alloc = [&](size_t bytes) -> char* {
    char* p = ws + off;
    off += (bytes + 255) & ~(size_t)255;
    return p;
  };
  u16* P1 = (u16*)alloc((size_t)NP * 256 * 2);
  u16* P2 = (u16*)alloc((size_t)NP * 256 * 2);
  u16* A1 = (u16*)alloc((size_t)NA * 256 * 2);
  u16* A2 = (u16*)alloc((size_t)NA * 256 * 2);
  u16* P3 = (u16*)alloc((size_t)NP * 256 * 2);   // hP1 (dual-GEMM output)
  float* ldAP_P = (float*)alloc((size_t)NP * 8 * 4);
  float* lsPA_P = (float*)alloc((size_t)NP * 8 * 4);
  float* lsPP_P = (float*)alloc((size_t)NP * 8 * 4);
  float* ldPP_P = (float*)alloc((size_t)NP * 8 * 4);
  float* lsAP_A = (float*)alloc((size_t)NA * 8 * 4);
  float* ldPA_A = (float*)alloc((size_t)NA * 8 * 4);
  u16* wtP0 = (u16*)alloc(256 * 512 * 2);
  u16* wtA0 = (u16*)alloc(256 * 256 * 2);
  u16* wtP1 = (u16*)alloc(256 * 256 * 2);
  u16* wtA1 = (u16*)alloc(256 * 256 * 2);
  u16* kwt0 = (u16*)alloc(256 * 256 * 2);
  u16* kwt1 = (u16*)alloc(256 * 256 * 2);
  u16* lwt = (u16*)alloc(32 * 256 * 2);
  int* rpAP = (int*)alloc((NP + 1) * 4);
  int* rpPP = (int*)alloc((NP + 1) * 4);
  int* rpPA = (int*)alloc((NA + 1) * 4);
  int* eiAP = (int*)alloc((size_t)EAP * 4);
  int* eiPP = (int*)alloc((size_t)EPP * 4);
  int* eiPA = (int*)alloc((size_t)EPA * 4);
  int* bsum = (int*)alloc(768 * 4);
  int* bbase = (int*)alloc(768 * 4);
  size_t zbytes = (size_t)(4 * NP + 2 * NA) * 4 + 4 * 256 * 4;
  char* zblock = alloc(zbytes);
  int* cntAP = (int*)zblock;
  int* cntPP = cntAP + NP;
  int* cntPA = cntPP + NP;
  int* curAP = cntPA + NA;
  int* curPP = curAP + NP;
  int* curPA = curPP + NP;
  float* cs = (float*)(curPA + NA);  // 4 x 256
  float* attnBuf = (float*)alloc(256);

  // Overlay views (no extra workspace):
  u16* XPB = P1;                      // [NP][512] bf16 spans exactly P1|P2
  u16* HP = A1;                       // [NP][256] bf16 spans exactly A1|A2
  u16* XAB = P1;                      // [NA][256] bf16, lives after XPB is dead
  u16* hA0 = P2;                      // [NA][256] bf16 = first half of P2
  u16* P2b = P2 + (size_t)NA * 256;   // [NA][256] bf16 = second half of P2 (newA)

  (void)hipMemsetAsync((void*)zblock, 0, zbytes, stream);

  // weight transposes (f32 -> bf16)
  k_transpose<<<CEILDIV(512 * 256, 256), 256, 0, stream>>>(W_P[0], wtP0, 512, 256);
  k_transpose<<<CEILDIV(256 * 256, 256), 256, 0, stream>>>(W_A[0], wtA0, 256, 256);
  k_transpose<<<CEILDIV(256 * 256, 256), 256, 0, stream>>>(W_P[1], wtP1, 256, 256);
  k_transpose<<<CEILDIV(256 * 256, 256), 256, 0, stream>>>(W_A[1], wtA1, 256, 256);
  k_transpose<<<CEILDIV(256 * 256, 256), 256, 0, stream>>>(kW[0], kwt0, 256, 256);
  k_transpose<<<CEILDIV(256 * 256, 256), 256, 0, stream>>>(kW[1], kwt1, 256, 256);
  k_transpose<<<CEILDIV(256 * 32, 256), 256, 0, stream>>>(linW, lwt, 256, 32);

  // CSR build (by dst), payload = src node id; shared by both layers
  k_hist<<<CEILDIV(EAP, 256), 256, 0, stream>>>(dstAP, EAP, cntAP);
  k_hist<<<CEILDIV(EPP, 256), 256, 0, stream>>>(dstPP, EPP, cntPP);
  k_hist<<<CEILDIV(EPA, 256), 256, 0, stream>>>(dstPA, EPA, cntPA);
  k_scan_a<<<245, 256, 0, stream>>>(cntAP, cntPP, cntPA, bsum);
  k_scan_b<<<1, 256, 0, stream>>>(bsum, bbase, rpAP, rpPP, rpPA);
  k_scan_c<<<245, 256, 0, stream>>>(cntAP, cntPP, cntPA, bbase, rpAP, rpPP, rpPA);
  k_scatter<<<CEILDIV(EAP, 256), 256, 0, stream>>>(dstAP, srcAP, EAP, rpAP, curAP, eiAP);
  k_scatter<<<CEILDIV(EPP, 256), 256, 0, stream>>>(dstPP, srcPP, EPP, rpPP, curPP, eiPP);
  k_scatter<<<CEILDIV(EPA, 256), 256, 0, stream>>>(dstPA, srcPA, EPA, rpPA, curPA, eiPA);

  auto G0 = [&](const u16* A, const u16* Bt, const float* bias, u16* Cb, int M, int N, int K) {
    dim3 g(CEILDIV(M, BM), CEILDIV(N, BN));
    k_gemm2<0, 0><<<g, 256, 0, stream>>>(A, nullptr, nullptr, Bt, bias, Cb, nullptr, nullptr, M, N, K);
  };
  auto G1 = [&](const u16* A, const u16* Bt, const float* bias, float* colsum, int M, int N, int K) {
    dim3 g(CEILDIV(M, BM), CEILDIV(N, BN));
    k_gemm2<0, 1><<<g, 256, 0, stream>>>(A, nullptr, nullptr, Bt, bias, nullptr, nullptr, colsum, M, N, K);
  };
  auto G0d = [&](const u16* A, const u16* A2v, const float* attn, const u16* Bt,
                 const float* bias, u16* Cb, int M, int N, int K) {
    dim3 g(CEILDIV(M, BM), CEILDIV(N, BN));
    k_gemm2<1, 0><<<g, 256, 0, stream>>>(A, A2v, attn, Bt, bias, Cb, nullptr, nullptr, M, N, K);
  };
  auto G2d = [&](const u16* A, const u16* A2v, const float* attn, const u16* Bt,
                 const float* bias, float* Cf, int M, int N, int K) {
    dim3 g(CEILDIV(M, BM), CEILDIV(N, BN));
    k_gemm2<1, 2><<<g, 256, 0, stream>>>(A, A2v, attn, Bt, bias, nullptr, Cf, nullptr, M, N, K);
  };

  // =================== Layer 0 ===================
  k_cvt<<<CEILDIV(NP * 512 / 8, 256), 256, 0, stream>>>(xP, XPB, NP * 512 / 8);
  G0(XPB, wtP0, b_P[0], HP, NP, 256, 512);   // hP -> HP (=A1|A2); XPB dead after this
  k_cvt<<<CEILDIV(NA * 256 / 8, 256), 256, 0, stream>>>(xA, XAB, NA * 256 / 8);
  G0(XAB, wtA0, b_A[0], hA0, NA, 256, 256);  // hA -> P2 first half; XAB dead after this

  k_logits<<<CEILDIV(NP * 8, 256), 256, 0, stream>>>(
      HP, NP, adAP[0], asPA[0], asPP[0], adPP[0], ldAP_P, lsPA_P, lsPP_P, ldPP_P);
  k_logits<<<CEILDIV(NA * 8, 256), 256, 0, stream>>>(
      hA0, NA, asAP[0], adPA[0], nullptr, nullptr, lsAP_A, ldPA_A, nullptr, nullptr);
  // PP: papers->papers (src hP=HP -> oPP=P1)
  k_attn_agg<<<CEILDIV(NP, 4), 256, 0, stream>>>(rpPP, eiPP, lsPP_P, ldPP_P, HP, P1, NP);
  // PA: papers->authors (src hP=HP -> oPA=newA=P2b)
  k_attn_agg<<<CEILDIV(NA, 4), 256, 0, stream>>>(rpPA, eiPA, lsPA_P, ldPA_A, HP, P2b, NA);
  // AP: authors->papers (src hA=hA0 -> oAP=HP; hP dead now)
  k_attn_agg<<<CEILDIV(NP, 4), 256, 0, stream>>>(rpAP, eiAP, lsAP_A, ldAP_P, hA0, HP, NP);
  // semantic over {oAP=HP, oPP=P1}
  G1(HP, kwt0, kb[0], cs, NP, 256, 256);
  G1(P1, kwt0, kb[0], cs + 256, NP, 256, 256);
  k_scores<<<1, 64, 0, stream>>>(cs, cs + 256, qv[0], 1.0f / NP, attnBuf);
  // fused semantic-combine + layer-1 paper projection:
  // hP1 = (a0*oAP + a1*oPP) @ W_P1 + b_P1 -> P3
  G0d(HP, P1, attnBuf, wtP1, b_P[1], P3, NP, 256, 256);

  // =================== Layer 1 ===================
  G0(P2b, wtA1, b_A[1], hA0, NA, 256, 256);  // hA1 -> P2 first half
  k_logits<<<CEILDIV(NP * 8, 256), 256, 0, stream>>>(
      P3, NP, adAP[1], asPA[1], asPP[1], adPP[1], ldAP_P, lsPA_P, lsPP_P, ldPP_P);
  k_logits<<<CEILDIV(NA * 8, 256), 256, 0, stream>>>(
      hA0, NA, asAP[1], adPA[1], nullptr, nullptr, lsAP_A, ldPA_A, nullptr, nullptr);
  // PP: src hP1=P3 -> oPP1=P1 (old oPP dead: consumed by dual GEMM)
  k_attn_agg<<<CEILDIV(NP, 4), 256, 0, stream>>>(rpPP, eiPP, lsPP_P, ldPP_P, P3, P1, NP);
  // AP: src hA1=hA0 -> oAP1=HP (old oAP dead: consumed by dual GEMM)
  k_attn_agg<<<CEILDIV(NP, 4), 256, 0, stream>>>(rpAP, eiAP, lsAP_A, ldAP_P, hA0, HP, NP);
  // semantic over {oAP1=HP, oPP1=P1}
  G1(HP, kwt1, kb[1], cs + 512, NP, 256, 256);
  G1(P1, kwt1, kb[1], cs + 768, NP, 256, 256);
  k_scores<<<1, 64, 0, stream>>>(cs + 512, cs + 768, qv[1], 1.0f / NP, attnBuf + 2);

  // classifier fused with semantic combine: d_out = (a0*oAP1 + a1*oPP1) @ linW + linb
  G2d(HP, P1, attnBuf + 2, lwt, linb, (float*)d_out, NP, 32, 256);
}

// Round 6
// 1380.089 us; speedup vs baseline: 1.7377x; 1.1912x over previous
//
#include <hip/hip_runtime.h>
#include <math.h>

typedef unsigned short u16;
typedef u16 ushort8 __attribute__((ext_vector_type(8)));
typedef __bf16 bf16x8 __attribute__((ext_vector_type(8)));
typedef float floatx4 __attribute__((ext_vector_type(4)));

__device__ __forceinline__ float bf2f(u16 u) {
  union { unsigned int i; float f; } v; v.i = ((unsigned int)u) << 16; return v.f;
}
__device__ __forceinline__ u16 f2bf(float f) {
  union { float f; unsigned int i; } v; v.f = f;
  return (u16)((v.i + 0x7fffu + ((v.i >> 16) & 1u)) >> 16);
}

#define CEILDIV(a, b) (((a) + (b) - 1) / (b))

// ---------------- async global->LDS, 16 B per lane ----------------
typedef const __attribute__((address_space(1))) unsigned int ga_u32;
typedef __attribute__((address_space(3))) unsigned int lds_u32;
__device__ __forceinline__ void gload16(const u16* g, u16* l) {
  __builtin_amdgcn_global_load_lds((ga_u32*)g, (lds_u32*)l, 16, 0, 0);
}

// ---------------- transpose+convert: W[K][N] (f32) -> Wt[N][K] (bf16) ----------------
__global__ void k_transpose(const float* __restrict__ W, u16* __restrict__ Wt, int K, int N) {
  int t = blockIdx.x * blockDim.x + threadIdx.x;
  if (t >= K * N) return;
  int n = t / K, k = t - n * K;
  Wt[t] = f2bf(W[k * N + n]);
}

// ---------------- CSR build ----------------
__global__ void k_hist(const int* __restrict__ dst, int E, int* __restrict__ cnt) {
  int t = blockIdx.x * blockDim.x + threadIdx.x;
  if (t < E) atomicAdd(&cnt[dst[t]], 1);
}

// ---- two-level exclusive scan, fused over 3 segments (AP:100k, PP:100k, PA:50k) ----
__device__ __forceinline__ void seg_map(int b, int& seg, int& bs, int& n) {
  if (b < 98) { seg = 0; bs = b; n = 100000; }
  else if (b < 196) { seg = 1; bs = b - 98; n = 100000; }
  else { seg = 2; bs = b - 196; n = 50000; }
}

__global__ __launch_bounds__(256) void k_scan_a(
    const int* __restrict__ c0, const int* __restrict__ c1, const int* __restrict__ c2,
    int* __restrict__ bsum) {
  int seg, bs, n;
  seg_map(blockIdx.x, seg, bs, n);
  const int* cnt = seg == 0 ? c0 : (seg == 1 ? c1 : c2);
  int t = threadIdx.x;
  int base = bs * 1024 + t * 4;
  int s = 0;
#pragma unroll
  for (int j = 0; j < 4; j++) { int i = base + j; if (i < n) s += cnt[i]; }
#pragma unroll
  for (int o = 1; o < 64; o <<= 1) s += __shfl_xor(s, o);
  __shared__ int wt[4];
  int lane = t & 63, w = t >> 6;
  if (lane == 0) wt[w] = s;
  __syncthreads();
  if (t == 0) bsum[seg * 256 + bs] = wt[0] + wt[1] + wt[2] + wt[3];
}

__global__ __launch_bounds__(256) void k_scan_b(
    const int* __restrict__ bsum, int* __restrict__ bbase,
    int* __restrict__ rp0, int* __restrict__ rp1, int* __restrict__ rp2) {
  __shared__ int sm[256];
  int t = threadIdx.x;
  for (int seg = 0; seg < 3; ++seg) {
    int nb = (seg == 2) ? 49 : 98;
    int n = (seg == 2) ? 50000 : 100000;
    int v = (t < nb) ? bsum[seg * 256 + t] : 0;
    sm[t] = v;
    __syncthreads();
    for (int o = 1; o < 256; o <<= 1) {
      int u = (t >= o) ? sm[t - o] : 0;
      __syncthreads();
      sm[t] += u;
      __syncthreads();
    }
    if (t < nb) bbase[seg * 256 + t] = sm[t] - v;
    if (t == 255) {
      int* rp = seg == 0 ? rp0 : (seg == 1 ? rp1 : rp2);
      rp[n] = sm[255];
    }
    __syncthreads();
  }
}

__global__ __launch_bounds__(256) void k_scan_c(
    const int* __restrict__ c0, const int* __restrict__ c1, const int* __restrict__ c2,
    const int* __restrict__ bbase,
    int* __restrict__ rp0, int* __restrict__ rp1, int* __restrict__ rp2) {
  int seg, bs, n;
  seg_map(blockIdx.x, seg, bs, n);
  const int* cnt = seg == 0 ? c0 : (seg == 1 ? c1 : c2);
  int* rp = seg == 0 ? rp0 : (seg == 1 ? rp1 : rp2);
  int t = threadIdx.x;
  int base = bs * 1024 + t * 4;
  int c[4];
  int s = 0;
#pragma unroll
  for (int j = 0; j < 4; j++) { int i = base + j; c[j] = (i < n) ? cnt[i] : 0; s += c[j]; }
  int lane = t & 63, w = t >> 6;
  int incl = s;
#pragma unroll
  for (int o = 1; o < 64; o <<= 1) { int u = __shfl_up(incl, o); if (lane >= o) incl += u; }
  __shared__ int wt[4];
  if (lane == 63) wt[w] = incl;
  __syncthreads();
  int wb = 0;
#pragma unroll
  for (int j = 0; j < 4; j++) if (j < w) wb += wt[j];
  int thr = bbase[seg * 256 + bs] + wb + incl - s;
#pragma unroll
  for (int j = 0; j < 4; j++) { int i = base + j; if (i < n) rp[i] = thr; thr += c[j]; }
}

// scatter stores SRC NODE directly (not edge id): kills one indirection in attn
__global__ void k_scatter(const int* __restrict__ dst, const int* __restrict__ src, int E,
                          const int* __restrict__ rp, int* __restrict__ cur,
                          int* __restrict__ esrc) {
  int t = blockIdx.x * blockDim.x + threadIdx.x;
  if (t >= E) return;
  int d = dst[t];
  int p = atomicAdd(&cur[d], 1);
  esrc[rp[d] + p] = src[t];
}

// ================= k_gemm3: full-width N=256 block, 512 thr / 8 waves =================
// C[M,256] = A[M,K] @ Bt[256,K]^T (+bias). A read ONCE per GEMM (grid.y == 1).
// SRC 0: bf16 A via global_load_lds. SRC 1: dual bf16 blend a0*A+a1*A2. SRC 2: f32 A (fused cvt).
// MODE 0: store bf16 Cb (LDS-transpose epilogue). MODE 1: fast-tanh colsum atomic.
#define G3_BM 128
#define G3_BN 256
#define G3_BK 32

template <int SRC, int MODE>
__global__ __launch_bounds__(512) void k_gemm3(
    const void* __restrict__ Av, const u16* __restrict__ A2, const float* __restrict__ attn,
    const u16* __restrict__ Bt, const float* __restrict__ bias,
    u16* __restrict__ Cb, float* __restrict__ colsum, int M, int K) {
  __shared__ __align__(16) u16 sm[2][(G3_BM + G3_BN) * G3_BK];  // 48 KiB
  int tid = threadIdx.x;
  int lane = tid & 63, wid = tid >> 6;   // 8 waves
  int wm = wid >> 2, wn = wid & 3;       // 2 x 4 wave grid, 64x64 per wave
  int quad = lane >> 4, l16 = lane & 15;
  int m0 = blockIdx.x * G3_BM;

  float a0s = 0.f, a1s = 0.f;
  if (SRC == 1) { a0s = attn[0]; a1s = attn[1]; }

  // staging: granule g = tid (A, B-chunk0), 512+tid (B-chunk1); 16 B each
  int gr_ = tid >> 2;                 // row within chunk (0..127)
  int gc_ = (tid & 3) * 8;            // u16 col (0/8/16/24)
  int arow = m0 + gr_; if (arow >= M) arow = M - 1;
  const u16* gaB = (SRC != 2) ? (const u16*)Av + (size_t)arow * K + gc_ : nullptr;
  const u16* ga2 = (SRC == 1) ? A2 + (size_t)arow * K + gc_ : nullptr;
  const float* gaF = (SRC == 2) ? (const float*)Av + (size_t)arow * K + gc_ : nullptr;
  const u16* gb0 = Bt + (size_t)gr_ * K + gc_;          // B rows 0..127
  const u16* gb1 = Bt + (size_t)(128 + gr_) * K + gc_;  // B rows 128..255
  // wave-uniform LDS bases (u16 units); HW adds lane*16B for gload16
  const int laA = wid * 512;
  const int laB0 = 4096 + wid * 512;
  const int laB1 = 8192 + wid * 512;

  floatx4 acc[4][4];
#pragma unroll
  for (int i = 0; i < 4; i++)
#pragma unroll
    for (int j = 0; j < 4; j++) acc[i][j] = (floatx4){0.f, 0.f, 0.f, 0.f};

  auto stage = [&](int buf, int k0) {
    u16* sa = sm[buf];
    if (SRC == 0) {
      gload16(gaB + k0, sa + laA);
    } else if (SRC == 2) {
      const floatx4* p = (const floatx4*)(gaF + k0);
      floatx4 v0 = p[0], v1 = p[1];
      u16 t[8];
#pragma unroll
      for (int j = 0; j < 4; j++) { t[j] = f2bf(v0[j]); t[4 + j] = f2bf(v1[j]); }
      *(ushort8*)(sa + laA + (lane << 3)) = *(ushort8*)t;
    } else {
      ushort8 u = *(const ushort8*)(gaB + k0);
      ushort8 w = *(const ushort8*)(ga2 + k0);
      u16 t[8];
#pragma unroll
      for (int j = 0; j < 8; j++) t[j] = f2bf(a0s * bf2f(u[j]) + a1s * bf2f(w[j]));
      *(ushort8*)(sa + laA + (lane << 3)) = *(ushort8*)t;
    }
    gload16(gb0 + k0, sa + laB0);
    gload16(gb1 + k0, sa + laB1);
  };

  stage(0, 0);
  __syncthreads();

  int nk = K / G3_BK;
  for (int t = 0; t < nk; ++t) {
    int cur = t & 1;
    if (t + 1 < nk) stage(cur ^ 1, (t + 1) * G3_BK);
    const u16* Ab = sm[cur];
    const u16* Bb = sm[cur] + G3_BM * G3_BK;
    bf16x8 af[4], bfr[4];
#pragma unroll
    for (int mi = 0; mi < 4; mi++)
      af[mi] = *(const bf16x8*)(Ab + (wm * 64 + mi * 16 + l16) * G3_BK + quad * 8);
#pragma unroll
    for (int ni = 0; ni < 4; ni++)
      bfr[ni] = *(const bf16x8*)(Bb + (wn * 64 + ni * 16 + l16) * G3_BK + quad * 8);
#pragma unroll
    for (int mi = 0; mi < 4; mi++)
#pragma unroll
      for (int ni = 0; ni < 4; ni++)
        acc[mi][ni] = __builtin_amdgcn_mfma_f32_16x16x32_bf16(af[mi], bfr[ni], acc[mi][ni], 0, 0, 0);
    __syncthreads();
  }

  if (MODE == 1) {
#pragma unroll
    for (int ni = 0; ni < 4; ni++) {
      int gc = wn * 64 + ni * 16 + l16;
      float bv = bias[gc];
      float part = 0.f;
#pragma unroll
      for (int mi = 0; mi < 4; mi++) {
#pragma unroll
        for (int r = 0; r < 4; r++) {
          int gr = m0 + wm * 64 + mi * 16 + quad * 4 + r;
          if (gr < M) {
            float v = acc[mi][ni][r] + bv;
            float e2 = __expf(2.f * v);           // fast tanh = 1 - 2/(e^{2v}+1)
            part += 1.f - 2.f / (e2 + 1.f);
          }
        }
      }
      part += __shfl_xor(part, 16);
      part += __shfl_xor(part, 32);
      if (lane < 16) atomicAdd(&colsum[gc], part);
    }
  } else {
    // LDS transpose epilogue: coalesced 32B/lane row stores (per-wave 16x68 f32 region)
    float* smf = (float*)sm;
    float* tw = smf + wid * 16 * 68;  // 8 x 4352 B = 34816 B <= 49152 B
#pragma unroll
    for (int mi = 0; mi < 4; mi++) {
#pragma unroll
      for (int ni = 0; ni < 4; ni++)
#pragma unroll
        for (int r = 0; r < 4; r++)
          tw[(quad * 4 + r) * 68 + ni * 16 + l16] = acc[mi][ni][r];
      int row = lane >> 2, cq = (lane & 3) * 16;
      int gr = m0 + wm * 64 + mi * 16 + row;
      if (gr < M) {
        int gc0 = wn * 64 + cq;
        u16 ob[16];
#pragma unroll
        for (int j = 0; j < 16; j++) ob[j] = f2bf(tw[row * 68 + cq + j] + bias[gc0 + j]);
        *(ushort8*)(Cb + (size_t)gr * 256 + gc0) = *(ushort8*)ob;
        *(ushort8*)(Cb + (size_t)gr * 256 + gc0 + 8) = *(ushort8*)(ob + 8);
      }
    }
  }
}

// ============ k_gemm2: 256-thr 128x128 kernel, kept ONLY for the N=32 classifier ============
#define BM 128
#define BN 128
#define BK 32

__global__ __launch_bounds__(256) void k_gemm2_cls(
    const u16* __restrict__ A, const u16* __restrict__ A2, const float* __restrict__ attn,
    const u16* __restrict__ Bt, const float* __restrict__ bias,
    float* __restrict__ Cf, int M, int N, int K) {
  __shared__ __align__(16) u16 sm[2][2][BM * BK];  // 32 KiB
  int tid = threadIdx.x;
  int lane = tid & 63, wid = tid >> 6;
  int wm = wid >> 1, wn = wid & 1;
  int quad = lane >> 4, l16 = lane & 15;
  int m0 = blockIdx.x * BM, n0 = 0;

  float a0s = attn[0], a1s = attn[1];

  int sr = lane >> 2;
  int sc = (lane & 3) * 8;
  int ra0 = m0 + wid * 32 + sr;
  int ra1 = ra0 + 16;
  int rb0 = n0 + wid * 32 + sr;
  int rb1 = rb0 + 16;
  if (ra0 >= M) ra0 = M - 1;
  if (ra1 >= M) ra1 = M - 1;
  if (rb0 >= N) rb0 = N - 1;
  if (rb1 >= N) rb1 = N - 1;
  const u16* ga0 = A + (size_t)ra0 * K + sc;
  const u16* ga1 = A + (size_t)ra1 * K + sc;
  const u16* g2a0 = A2 + (size_t)ra0 * K + sc;
  const u16* g2a1 = A2 + (size_t)ra1 * K + sc;
  const u16* gb0 = Bt + (size_t)rb0 * K + sc;
  const u16* gb1 = Bt + (size_t)rb1 * K + sc;
  const int la = wid * 32 * BK;
  const int lb = la + 16 * BK;

  floatx4 acc[4][4];
#pragma unroll
  for (int i = 0; i < 4; i++)
#pragma unroll
    for (int j = 0; j < 4; j++) acc[i][j] = (floatx4){0.f, 0.f, 0.f, 0.f};

  auto stage = [&](int buf, int k0) {
    u16* sa = &sm[buf][0][0];
    u16* sb = &sm[buf][1][0];
    ushort8 u0 = *(const ushort8*)(ga0 + k0);
    ushort8 w0 = *(const ushort8*)(g2a0 + k0);
    ushort8 u1 = *(const ushort8*)(ga1 + k0);
    ushort8 w1 = *(const ushort8*)(g2a1 + k0);
    u16 t0[8], t1[8];
#pragma unroll
    for (int j = 0; j < 8; j++) {
      t0[j] = f2bf(a0s * bf2f(u0[j]) + a1s * bf2f(w0[j]));
      t1[j] = f2bf(a0s * bf2f(u1[j]) + a1s * bf2f(w1[j]));
    }
    *(ushort8*)(sa + la + lane * 8) = *(ushort8*)t0;
    *(ushort8*)(sa + lb + lane * 8) = *(ushort8*)t1;
    gload16(gb0 + k0, sb + la);
    gload16(gb1 + k0, sb + lb);
  };

  stage(0, 0);
  __syncthreads();

  int nk = K / BK;
  for (int t = 0; t < nk; ++t) {
    int cur = t & 1;
    if (t + 1 < nk) stage(cur ^ 1, (t + 1) * BK);
    const u16* Ab = &sm[cur][0][0];
    const u16* Bb = &sm[cur][1][0];
    bf16x8 af[4], bfr[4];
#pragma unroll
    for (int mi = 0; mi < 4; mi++)
      af[mi] = *(const bf16x8*)(Ab + (wm * 64 + mi * 16 + l16) * BK + quad * 8);
#pragma unroll
    for (int ni = 0; ni < 4; ni++)
      bfr[ni] = *(const bf16x8*)(Bb + (wn * 64 + ni * 16 + l16) * BK + quad * 8);
#pragma unroll
    for (int mi = 0; mi < 4; mi++)
#pragma unroll
      for (int ni = 0; ni < 4; ni++)
        acc[mi][ni] = __builtin_amdgcn_mfma_f32_16x16x32_bf16(af[mi], bfr[ni], acc[mi][ni], 0, 0, 0);
    __syncthreads();
  }

#pragma unroll
  for (int ni = 0; ni < 4; ni++) {
    int gc = n0 + wn * 64 + ni * 16 + l16;
    if (gc >= N) continue;
    float bv = bias[gc];
#pragma unroll
    for (int mi = 0; mi < 4; mi++) {
#pragma unroll
      for (int r = 0; r < 4; r++) {
        int gr = m0 + wm * 64 + mi * 16 + quad * 4 + r;
        if (gr < M) Cf[(size_t)gr * N + gc] = acc[mi][ni][r] + bv;
      }
    }
  }
}

// ---------------- per-node attention logits ----------------
__global__ void k_logits(const u16* __restrict__ h, int N,
                         const float* __restrict__ a0, const float* __restrict__ a1,
                         const float* __restrict__ a2, const float* __restrict__ a3,
                         float* __restrict__ o0, float* __restrict__ o1,
                         float* __restrict__ o2, float* __restrict__ o3) {
  int t = blockIdx.x * blockDim.x + threadIdx.x;
  int n = t >> 3, hh = t & 7;
  if (n >= N) return;
  const ushort8* hp = (const ushort8*)(h + (size_t)n * 256 + hh * 32);
  float d0 = 0.f, d1 = 0.f, d2 = 0.f, d3 = 0.f;
#pragma unroll
  for (int q = 0; q < 4; q++) {
    ushort8 v = hp[q];
#pragma unroll
    for (int j = 0; j < 8; j++) {
      float f = bf2f(v[j]);
      int idx = hh * 32 + q * 8 + j;
      d0 += f * a0[idx];
      d1 += f * a1[idx];
      if (a2) d2 += f * a2[idx];
      if (a3) d3 += f * a3[idx];
    }
  }
  o0[t] = d0;
  o1[t] = d1;
  if (o2) o2[t] = d2;
  if (o3) o3[t] = d3;
}

// ---------------- fused softmax + aggregate: SINGLE-PASS online, one wave per dst ----------------
__global__ __launch_bounds__(256) void k_attn_agg(
    const int* __restrict__ rp, const int* __restrict__ esrc,
    const float* __restrict__ als, const float* __restrict__ ald,
    const u16* __restrict__ hsrc, u16* __restrict__ out, int Ndst) {
  int wid = threadIdx.x >> 6, lane = threadIdx.x & 63;
  int n = blockIdx.x * 4 + wid;
  if (n >= Ndst) return;
  int hh = lane >> 3;
  int b = rp[n], e = rp[n + 1];
  float av = ald[n * 8 + hh];
  float m = -1e30f, s = 0.f;
  float a0 = 0.f, a1 = 0.f, a2 = 0.f, a3 = 0.f;
  int i = b;
  for (; i + 1 < e; i += 2) {
    int s0 = esrc[i], s1 = esrc[i + 1];
    float x0 = als[s0 * 8 + hh] + av, x1 = als[s1 * 8 + hh] + av;
    ushort4 v0 = *(const ushort4*)(hsrc + (size_t)s0 * 256 + lane * 4);
    ushort4 v1 = *(const ushort4*)(hsrc + (size_t)s1 * 256 + lane * 4);
    x0 = x0 > 0.f ? x0 : 0.2f * x0;
    x1 = x1 > 0.f ? x1 : 0.2f * x1;
    float mx = fmaxf(x0, x1);
    if (mx > m) {
      float r = __expf(m - mx);
      s *= r; a0 *= r; a1 *= r; a2 *= r; a3 *= r;
      m = mx;
    }
    float w0 = __expf(x0 - m), w1 = __expf(x1 - m);
    s += w0 + w1;
    a0 += w0 * bf2f(v0.x) + w1 * bf2f(v1.x);
    a1 += w0 * bf2f(v0.y) + w1 * bf2f(v1.y);
    a2 += w0 * bf2f(v0.z) + w1 * bf2f(v1.z);
    a3 += w0 * bf2f(v0.w) + w1 * bf2f(v1.w);
  }
  if (i < e) {
    int s0 = esrc[i];
    float x0 = als[s0 * 8 + hh] + av;
    ushort4 v0 = *(const ushort4*)(hsrc + (size_t)s0 * 256 + lane * 4);
    x0 = x0 > 0.f ? x0 : 0.2f * x0;
    if (x0 > m) {
      float r = __expf(m - x0);
      s *= r; a0 *= r; a1 *= r; a2 *= r; a3 *= r;
      m = x0;
    }
    float w0 = __expf(x0 - m);
    s += w0;
    a0 += w0 * bf2f(v0.x);
    a1 += w0 * bf2f(v0.y);
    a2 += w0 * bf2f(v0.z);
    a3 += w0 * bf2f(v0.w);
  }
  float inv = 1.f / (s + 1e-16f);
  a0 *= inv; a1 *= inv; a2 *= inv; a3 *= inv;
  ushort4 o;
  o.x = f2bf(a0 > 0.f ? a0 : 0.f);
  o.y = f2bf(a1 > 0.f ? a1 : 0.f);
  o.z = f2bf(a2 > 0.f ? a2 : 0.f);
  o.w = f2bf(a3 > 0.f ? a3 : 0.f);
  *(ushort4*)(out + (size_t)n * 256 + lane * 4) = o;
}

// ---------------- semantic attention scores (K=2) ----------------
__global__ void k_scores(const float* __restrict__ cs0, const float* __restrict__ cs1,
                         const float* __restrict__ q, float invN, float* __restrict__ attn) {
  int lane = threadIdx.x;
  float p0 = 0.f, p1 = 0.f;
  for (int f = lane; f < 256; f += 64) {
    float qv = q[f];
    p0 += qv * cs0[f];
    p1 += qv * cs1[f];
  }
  for (int o = 32; o > 0; o >>= 1) {
    p0 += __shfl_down(p0, o);
    p1 += __shfl_down(p1, o);
  }
  if (lane == 0) {
    float s0 = p0 * invN, s1 = p1 * invN;
    float mx = fmaxf(s0, s1);
    float e0 = __expf(s0 - mx), e1 = __expf(s1 - mx);
    float den = e0 + e1;
    attn[0] = e0 / den;
    attn[1] = e1 / den;
  }
}

extern "C" void kernel_launch(void* const* d_in, const int* in_sizes, int n_in,
                              void* d_out, int out_size, void* d_ws, size_t ws_size,
                              hipStream_t stream) {
  const int NP = 100000, NA = 50000;
  const int EAP = 300000, EPA = 300000, EPP = 500000;

  const float* xP = (const float*)d_in[0];
  const float* xA = (const float*)d_in[1];
  const int* srcAP = (const int*)d_in[2];
  const int* dstAP = (const int*)d_in[3];
  const int* srcPA = (const int*)d_in[4];
  const int* dstPA = (const int*)d_in[5];
  const int* srcPP = (const int*)d_in[6];
  const int* dstPP = (const int*)d_in[7];
  const float *W_P[2], *b_P[2], *W_A[2], *b_A[2];
  const float *asAP[2], *adAP[2], *asPA[2], *adPA[2], *asPP[2], *adPP[2];
  const float *kW[2], *kb[2], *qv[2];
  for (int l = 0; l < 2; ++l) {
    int base = 8 + l * 13;
    W_P[l] = (const float*)d_in[base + 0];
    b_P[l] = (const float*)d_in[base + 1];
    W_A[l] = (const float*)d_in[base + 2];
    b_A[l] = (const float*)d_in[base + 3];
    asAP[l] = (const float*)d_in[base + 4];
    adAP[l] = (const float*)d_in[base + 5];
    asPA[l] = (const float*)d_in[base + 6];
    adPA[l] = (const float*)d_in[base + 7];
    asPP[l] = (const float*)d_in[base + 8];
    adPP[l] = (const float*)d_in[base + 9];
    kW[l] = (const float*)d_in[base + 10];
    kb[l] = (const float*)d_in[base + 11];
    qv[l] = (const float*)d_in[base + 12];
  }
  const float* linW = (const float*)d_in[34];
  const float* linb = (const float*)d_in[35];

  // ---------------- workspace layout ----------------
  char* ws = (char*)d_ws;
  size_t off = 0;
  auto alloc = [&](size_t bytes) -> char* {
    char* p = ws + off;
    off += (bytes + 255) & ~(size_t)255;
    return p;
  };
  u16* P1 = (u16*)alloc((size_t)NP * 256 * 2);
  u16* P2 = (u16*)alloc((size_t)NP * 256 * 2);
  u16* A1 = (u16*)alloc((size_t)NA * 256 * 2);
  u16* A2 = (u16*)alloc((size_t)NA * 256 * 2);
  u16* P3 = (u16*)alloc((size_t)NP * 256 * 2);   // hP1 (dual-GEMM output)
  float* ldAP_P = (float*)alloc((size_t)NP * 8 * 4);
  float* lsPA_P = (float*)alloc((size_t)NP * 8 * 4);
  float* lsPP_P = (float*)alloc((size_t)NP * 8 * 4);
  float* ldPP_P = (float*)alloc((size_t)NP * 8 * 4);
  float* lsAP_A = (float*)alloc((size_t)NA * 8 * 4);
  float* ldPA_A = (float*)alloc((size_t)NA * 8 * 4);
  u16* wtP0 = (u16*)alloc(256 * 512 * 2);
  u16* wtA0 = (u16*)alloc(256 * 256 * 2);
  u16* wtP1 = (u16*)alloc(256 * 256 * 2);
  u16* wtA1 = (u16*)alloc(256 * 256 * 2);
  u16* kwt0 = (u16*)alloc(256 * 256 * 2);
  u16* kwt1 = (u16*)alloc(256 * 256 * 2);
  u16* lwt = (u16*)alloc(32 * 256 * 2);
  int* rpAP = (int*)alloc((NP + 1) * 4);
  int* rpPP = (int*)alloc((NP + 1) * 4);
  int* rpPA = (int*)alloc((NA + 1) * 4);
  int* eiAP = (int*)alloc((size_t)EAP * 4);
  int* eiPP = (int*)alloc((size_t)EPP * 4);
  int* eiPA = (int*)alloc((size_t)EPA * 4);
  int* bsum = (int*)alloc(768 * 4);
  int* bbase = (int*)alloc(768 * 4);
  size_t zbytes = (size_t)(4 * NP + 2 * NA) * 4 + 4 * 256 * 4;
  char* zblock = alloc(zbytes);
  int* cntAP = (int*)zblock;
  int* cntPP = cntAP + NP;
  int* cntPA = cntPP + NP;
  int* curAP = cntPA + NA;
  int* curPP = curAP + NP;
  int* curPA = curPP + NP;
  float* cs = (float*)(curPA + NA);  // 4 x 256
  float* attnBuf = (float*)alloc(256);

  // Overlay views (no extra workspace):
  u16* HP = A1;                       // [NP][256] bf16 spans exactly A1|A2
  u16* hA0 = P2;                      // [NA][256] bf16 = first half of P2
  u16* P2b = P2 + (size_t)NA * 256;   // [NA][256] bf16 = second half of P2 (newA)

  (void)hipMemsetAsync((void*)zblock, 0, zbytes, stream);

  // weight transposes (f32 -> bf16)
  k_transpose<<<CEILDIV(512 * 256, 256), 256, 0, stream>>>(W_P[0], wtP0, 512, 256);
  k_transpose<<<CEILDIV(256 * 256, 256), 256, 0, stream>>>(W_A[0], wtA0, 256, 256);
  k_transpose<<<CEILDIV(256 * 256, 256), 256, 0, stream>>>(W_P[1], wtP1, 256, 256);
  k_transpose<<<CEILDIV(256 * 256, 256), 256, 0, stream>>>(W_A[1], wtA1, 256, 256);
  k_transpose<<<CEILDIV(256 * 256, 256), 256, 0, stream>>>(kW[0], kwt0, 256, 256);
  k_transpose<<<CEILDIV(256 * 256, 256), 256, 0, stream>>>(kW[1], kwt1, 256, 256);
  k_transpose<<<CEILDIV(256 * 32, 256), 256, 0, stream>>>(linW, lwt, 256, 32);

  // CSR build (by dst), payload = src node id; shared by both layers
  k_hist<<<CEILDIV(EAP, 256), 256, 0, stream>>>(dstAP, EAP, cntAP);
  k_hist<<<CEILDIV(EPP, 256), 256, 0, stream>>>(dstPP, EPP, cntPP);
  k_hist<<<CEILDIV(EPA, 256), 256, 0, stream>>>(dstPA, EPA, cntPA);
  k_scan_a<<<245, 256, 0, stream>>>(cntAP, cntPP, cntPA, bsum);
  k_scan_b<<<1, 256, 0, stream>>>(bsum, bbase, rpAP, rpPP, rpPA);
  k_scan_c<<<245, 256, 0, stream>>>(cntAP, cntPP, cntPA, bbase, rpAP, rpPP, rpPA);
  k_scatter<<<CEILDIV(EAP, 256), 256, 0, stream>>>(dstAP, srcAP, EAP, rpAP, curAP, eiAP);
  k_scatter<<<CEILDIV(EPP, 256), 256, 0, stream>>>(dstPP, srcPP, EPP, rpPP, curPP, eiPP);
  k_scatter<<<CEILDIV(EPA, 256), 256, 0, stream>>>(dstPA, srcPA, EPA, rpPA, curPA, eiPA);

  int gP = CEILDIV(NP, G3_BM), gA = CEILDIV(NA, G3_BM);

  // =================== Layer 0 ===================
  // projections read f32 inputs directly (fused convert in staging)
  k_gemm3<2, 0><<<gP, 512, 0, stream>>>(xP, nullptr, nullptr, wtP0, b_P[0], HP, nullptr, NP, 512);
  k_gemm3<2, 0><<<gA, 512, 0, stream>>>(xA, nullptr, nullptr, wtA0, b_A[0], hA0, nullptr, NA, 256);

  k_logits<<<CEILDIV(NP * 8, 256), 256, 0, stream>>>(
      HP, NP, adAP[0], asPA[0], asPP[0], adPP[0], ldAP_P, lsPA_P, lsPP_P, ldPP_P);
  k_logits<<<CEILDIV(NA * 8, 256), 256, 0, stream>>>(
      hA0, NA, asAP[0], adPA[0], nullptr, nullptr, lsAP_A, ldPA_A, nullptr, nullptr);
  // PP: papers->papers (src hP=HP -> oPP=P1)
  k_attn_agg<<<CEILDIV(NP, 4), 256, 0, stream>>>(rpPP, eiPP, lsPP_P, ldPP_P, HP, P1, NP);
  // PA: papers->authors (src hP=HP -> oPA=newA=P2b)
  k_attn_agg<<<CEILDIV(NA, 4), 256, 0, stream>>>(rpPA, eiPA, lsPA_P, ldPA_A, HP, P2b, NA);
  // AP: authors->papers (src hA=hA0 -> oAP=HP; hP dead now)
  k_attn_agg<<<CEILDIV(NP, 4), 256, 0, stream>>>(rpAP, eiAP, lsAP_A, ldAP_P, hA0, HP, NP);
  // semantic over {oAP=HP, oPP=P1}
  k_gemm3<0, 1><<<gP, 512, 0, stream>>>(HP, nullptr, nullptr, kwt0, kb[0], nullptr, cs, NP, 256);
  k_gemm3<0, 1><<<gP, 512, 0, stream>>>(P1, nullptr, nullptr, kwt0, kb[0], nullptr, cs + 256, NP, 256);
  k_scores<<<1, 64, 0, stream>>>(cs, cs + 256, qv[0], 1.0f / NP, attnBuf);
  // fused semantic-combine + layer-1 paper projection: hP1 = (a0*oAP + a1*oPP) @ W_P1 + b_P1
  k_gemm3<1, 0><<<gP, 512, 0, stream>>>(HP, P1, attnBuf, wtP1, b_P[1], P3, nullptr, NP, 256);

  // =================== Layer 1 ===================
  k_gemm3<0, 0><<<gA, 512, 0, stream>>>(P2b, nullptr, nullptr, wtA1, b_A[1], hA0, nullptr, NA, 256);
  k_logits<<<CEILDIV(NP * 8, 256), 256, 0, stream>>>(
      P3, NP, adAP[1], asPA[1], asPP[1], adPP[1], ldAP_P, lsPA_P, lsPP_P, ldPP_P);
  k_logits<<<CEILDIV(NA * 8, 256), 256, 0, stream>>>(
      hA0, NA, asAP[1], adPA[1], nullptr, nullptr, lsAP_A, ldPA_A, nullptr, nullptr);
  // PP: src hP1=P3 -> oPP1=P1
  k_attn_agg<<<CEILDIV(NP, 4), 256, 0, stream>>>(rpPP, eiPP, lsPP_P, ldPP_P, P3, P1, NP);
  // AP: src hA1=hA0 -> oAP1=HP
  k_attn_agg<<<CEILDIV(NP, 4), 256, 0, stream>>>(rpAP, eiAP, lsAP_A, ldAP_P, hA0, HP, NP);
  // semantic over {oAP1=HP, oPP1=P1}
  k_gemm3<0, 1><<<gP, 512, 0, stream>>>(HP, nullptr, nullptr, kwt1, kb[1], nullptr, cs + 512, NP, 256);
  k_gemm3<0, 1><<<gP, 512, 0, stream>>>(P1, nullptr, nullptr, kwt1, kb[1], nullptr, cs + 768, NP, 256);
  k_scores<<<1, 64, 0, stream>>>(cs + 512, cs + 768, qv[1], 1.0f / NP, attnBuf + 2);

  // classifier fused with semantic combine: d_out = (a0*oAP1 + a1*oPP1) @ linW + linb
  k_gemm2_cls<<<CEILDIV(NP, BM), 256, 0, stream>>>(
      HP, P1, attnBuf + 2, lwt, linb, (float*)d_out, NP, 32, 256);
}

// Round 7
// 1369.650 us; speedup vs baseline: 1.7509x; 1.0076x over previous
//
#include <hip/hip_runtime.h>
#include <math.h>

typedef unsigned short u16;
typedef u16 ushort8 __attribute__((ext_vector_type(8)));
typedef __bf16 bf16x8 __attribute__((ext_vector_type(8)));
typedef float floatx4 __attribute__((ext_vector_type(4)));

__device__ __forceinline__ float bf2f(u16 u) {
  union { unsigned int i; float f; } v; v.i = ((unsigned int)u) << 16; return v.f;
}
__device__ __forceinline__ u16 f2bf(float f) {
  union { float f; unsigned int i; } v; v.f = f;
  return (u16)((v.i + 0x7fffu + ((v.i >> 16) & 1u)) >> 16);
}

#define CEILDIV(a, b) (((a) + (b) - 1) / (b))

// ---------------- async global->LDS, 16 B per lane ----------------
typedef const __attribute__((address_space(1))) unsigned int ga_u32;
typedef __attribute__((address_space(3))) unsigned int lds_u32;
__device__ __forceinline__ void gload16(const u16* g, u16* l) {
  __builtin_amdgcn_global_load_lds((ga_u32*)g, (lds_u32*)l, 16, 0, 0);
}

// ---------------- transpose+convert: W[K][N] (f32) -> Wt[N][K] (bf16) ----------------
__global__ void k_transpose(const float* __restrict__ W, u16* __restrict__ Wt, int K, int N) {
  int t = blockIdx.x * blockDim.x + threadIdx.x;
  if (t >= K * N) return;
  int n = t / K, k = t - n * K;
  Wt[t] = f2bf(W[k * N + n]);
}

// ---------------- CSR build: fused 3-segment hist / scatter ----------------
__global__ void k_hist3(const int* __restrict__ d0, int E0, int* __restrict__ c0,
                        const int* __restrict__ d1, int E1, int* __restrict__ c1,
                        const int* __restrict__ d2, int E2, int* __restrict__ c2) {
  int t = blockIdx.x * blockDim.x + threadIdx.x;
  if (t < E0) atomicAdd(&c0[d0[t]], 1);
  else if (t < E0 + E1) atomicAdd(&c1[d1[t - E0]], 1);
  else if (t < E0 + E1 + E2) atomicAdd(&c2[d2[t - E0 - E1]], 1);
}

__global__ void k_scatter3(
    const int* __restrict__ d0, const int* __restrict__ s0v, int E0,
    const int* __restrict__ rp0, int* __restrict__ cur0, int* __restrict__ es0,
    const int* __restrict__ d1, const int* __restrict__ s1v, int E1,
    const int* __restrict__ rp1, int* __restrict__ cur1, int* __restrict__ es1,
    const int* __restrict__ d2, const int* __restrict__ s2v, int E2,
    const int* __restrict__ rp2, int* __restrict__ cur2, int* __restrict__ es2) {
  int t = blockIdx.x * blockDim.x + threadIdx.x;
  if (t < E0) {
    int d = d0[t];
    int p = atomicAdd(&cur0[d], 1);
    es0[rp0[d] + p] = s0v[t];
  } else if (t < E0 + E1) {
    int u = t - E0;
    int d = d1[u];
    int p = atomicAdd(&cur1[d], 1);
    es1[rp1[d] + p] = s1v[u];
  } else if (t < E0 + E1 + E2) {
    int u = t - E0 - E1;
    int d = d2[u];
    int p = atomicAdd(&cur2[d], 1);
    es2[rp2[d] + p] = s2v[u];
  }
}

// ---- two-level exclusive scan, fused over 3 segments (AP:100k, PP:100k, PA:50k) ----
__device__ __forceinline__ void seg_map(int b, int& seg, int& bs, int& n) {
  if (b < 98) { seg = 0; bs = b; n = 100000; }
  else if (b < 196) { seg = 1; bs = b - 98; n = 100000; }
  else { seg = 2; bs = b - 196; n = 50000; }
}

__global__ __launch_bounds__(256) void k_scan_a(
    const int* __restrict__ c0, const int* __restrict__ c1, const int* __restrict__ c2,
    int* __restrict__ bsum) {
  int seg, bs, n;
  seg_map(blockIdx.x, seg, bs, n);
  const int* cnt = seg == 0 ? c0 : (seg == 1 ? c1 : c2);
  int t = threadIdx.x;
  int base = bs * 1024 + t * 4;
  int s = 0;
#pragma unroll
  for (int j = 0; j < 4; j++) { int i = base + j; if (i < n) s += cnt[i]; }
#pragma unroll
  for (int o = 1; o < 64; o <<= 1) s += __shfl_xor(s, o);
  __shared__ int wt[4];
  int lane = t & 63, w = t >> 6;
  if (lane == 0) wt[w] = s;
  __syncthreads();
  if (t == 0) bsum[seg * 256 + bs] = wt[0] + wt[1] + wt[2] + wt[3];
}

__global__ __launch_bounds__(256) void k_scan_b(
    const int* __restrict__ bsum, int* __restrict__ bbase,
    int* __restrict__ rp0, int* __restrict__ rp1, int* __restrict__ rp2) {
  __shared__ int sm[256];
  int t = threadIdx.x;
  for (int seg = 0; seg < 3; ++seg) {
    int nb = (seg == 2) ? 49 : 98;
    int n = (seg == 2) ? 50000 : 100000;
    int v = (t < nb) ? bsum[seg * 256 + t] : 0;
    sm[t] = v;
    __syncthreads();
    for (int o = 1; o < 256; o <<= 1) {
      int u = (t >= o) ? sm[t - o] : 0;
      __syncthreads();
      sm[t] += u;
      __syncthreads();
    }
    if (t < nb) bbase[seg * 256 + t] = sm[t] - v;
    if (t == 255) {
      int* rp = seg == 0 ? rp0 : (seg == 1 ? rp1 : rp2);
      rp[n] = sm[255];
    }
    __syncthreads();
  }
}

__global__ __launch_bounds__(256) void k_scan_c(
    const int* __restrict__ c0, const int* __restrict__ c1, const int* __restrict__ c2,
    const int* __restrict__ bbase,
    int* __restrict__ rp0, int* __restrict__ rp1, int* __restrict__ rp2) {
  int seg, bs, n;
  seg_map(blockIdx.x, seg, bs, n);
  const int* cnt = seg == 0 ? c0 : (seg == 1 ? c1 : c2);
  int* rp = seg == 0 ? rp0 : (seg == 1 ? rp1 : rp2);
  int t = threadIdx.x;
  int base = bs * 1024 + t * 4;
  int c[4];
  int s = 0;
#pragma unroll
  for (int j = 0; j < 4; j++) { int i = base + j; c[j] = (i < n) ? cnt[i] : 0; s += c[j]; }
  int lane = t & 63, w = t >> 6;
  int incl = s;
#pragma unroll
  for (int o = 1; o < 64; o <<= 1) { int u = __shfl_up(incl, o); if (lane >= o) incl += u; }
  __shared__ int wt[4];
  if (lane == 63) wt[w] = incl;
  __syncthreads();
  int wb = 0;
#pragma unroll
  for (int j = 0; j < 4; j++) if (j < w) wb += wt[j];
  int thr = bbase[seg * 256 + bs] + wb + incl - s;
#pragma unroll
  for (int j = 0; j < 4; j++) { int i = base + j; if (i < n) rp[i] = thr; thr += c[j]; }
}

// ================= k_gemm3: full-width N=256 block, 512 thr / 8 waves =================
// __launch_bounds__(512,4): cap VGPR at 128 -> 2 blocks/CU (16 waves) instead of 1.
// SRC 0: bf16 A via global_load_lds. SRC 1: dual bf16 blend a0*A+a1*A2. SRC 2: f32 A (fused cvt).
// MODE 0: store bf16 Cb (LDS-transpose epilogue). MODE 1: fast-tanh colsum atomic.
#define G3_BM 128
#define G3_BN 256
#define G3_BK 32

template <int SRC, int MODE>
__global__ __launch_bounds__(512, 4) void k_gemm3(
    const void* __restrict__ Av, const u16* __restrict__ A2, const float* __restrict__ attn,
    const u16* __restrict__ Bt, const float* __restrict__ bias,
    u16* __restrict__ Cb, float* __restrict__ colsum, int M, int K) {
  __shared__ __align__(16) u16 sm[2][(G3_BM + G3_BN) * G3_BK];  // 48 KiB
  int tid = threadIdx.x;
  int lane = tid & 63, wid = tid >> 6;   // 8 waves
  int wm = wid >> 2, wn = wid & 3;       // 2 x 4 wave grid, 64x64 per wave
  int quad = lane >> 4, l16 = lane & 15;
  int m0 = blockIdx.x * G3_BM;

  float a0s = 0.f, a1s = 0.f;
  if (SRC == 1) { a0s = attn[0]; a1s = attn[1]; }

  // staging: granule g = tid (A, B-chunk0), 512+tid (B-chunk1); 16 B each
  int gr_ = tid >> 2;                 // row within chunk (0..127)
  int gc_ = (tid & 3) * 8;            // u16 col (0/8/16/24)
  int arow = m0 + gr_; if (arow >= M) arow = M - 1;
  const u16* gaB = (SRC != 2) ? (const u16*)Av + (size_t)arow * K + gc_ : nullptr;
  const u16* ga2 = (SRC == 1) ? A2 + (size_t)arow * K + gc_ : nullptr;
  const float* gaF = (SRC == 2) ? (const float*)Av + (size_t)arow * K + gc_ : nullptr;
  const u16* gb0 = Bt + (size_t)gr_ * K + gc_;          // B rows 0..127
  const u16* gb1 = Bt + (size_t)(128 + gr_) * K + gc_;  // B rows 128..255
  // wave-uniform LDS bases (u16 units); HW adds lane*16B for gload16
  const int laA = wid * 512;
  const int laB0 = 4096 + wid * 512;
  const int laB1 = 8192 + wid * 512;

  floatx4 acc[4][4];
#pragma unroll
  for (int i = 0; i < 4; i++)
#pragma unroll
    for (int j = 0; j < 4; j++) acc[i][j] = (floatx4){0.f, 0.f, 0.f, 0.f};

  auto stage = [&](int buf, int k0) {
    u16* sa = sm[buf];
    if (SRC == 0) {
      gload16(gaB + k0, sa + laA);
    } else if (SRC == 2) {
      const floatx4* p = (const floatx4*)(gaF + k0);
      floatx4 v0 = p[0], v1 = p[1];
      u16 t[8];
#pragma unroll
      for (int j = 0; j < 4; j++) { t[j] = f2bf(v0[j]); t[4 + j] = f2bf(v1[j]); }
      *(ushort8*)(sa + laA + (lane << 3)) = *(ushort8*)t;
    } else {
      ushort8 u = *(const ushort8*)(gaB + k0);
      ushort8 w = *(const ushort8*)(ga2 + k0);
      u16 t[8];
#pragma unroll
      for (int j = 0; j < 8; j++) t[j] = f2bf(a0s * bf2f(u[j]) + a1s * bf2f(w[j]));
      *(ushort8*)(sa + laA + (lane << 3)) = *(ushort8*)t;
    }
    gload16(gb0 + k0, sa + laB0);
    gload16(gb1 + k0, sa + laB1);
  };

  stage(0, 0);
  __syncthreads();

  int nk = K / G3_BK;
  for (int t = 0; t < nk; ++t) {
    int cur = t & 1;
    if (t + 1 < nk) stage(cur ^ 1, (t + 1) * G3_BK);
    const u16* Ab = sm[cur];
    const u16* Bb = sm[cur] + G3_BM * G3_BK;
    bf16x8 af[4], bfr[4];
#pragma unroll
    for (int mi = 0; mi < 4; mi++)
      af[mi] = *(const bf16x8*)(Ab + (wm * 64 + mi * 16 + l16) * G3_BK + quad * 8);
#pragma unroll
    for (int ni = 0; ni < 4; ni++)
      bfr[ni] = *(const bf16x8*)(Bb + (wn * 64 + ni * 16 + l16) * G3_BK + quad * 8);
#pragma unroll
    for (int mi = 0; mi < 4; mi++)
#pragma unroll
      for (int ni = 0; ni < 4; ni++)
        acc[mi][ni] = __builtin_amdgcn_mfma_f32_16x16x32_bf16(af[mi], bfr[ni], acc[mi][ni], 0, 0, 0);
    __syncthreads();
  }

  if (MODE == 1) {
#pragma unroll
    for (int ni = 0; ni < 4; ni++) {
      int gc = wn * 64 + ni * 16 + l16;
      float bv = bias[gc];
      float part = 0.f;
#pragma unroll
      for (int mi = 0; mi < 4; mi++) {
#pragma unroll
        for (int r = 0; r < 4; r++) {
          int gr = m0 + wm * 64 + mi * 16 + quad * 4 + r;
          if (gr < M) {
            float v = acc[mi][ni][r] + bv;
            float e2 = __expf(2.f * v);           // fast tanh = 1 - 2/(e^{2v}+1)
            part += 1.f - 2.f / (e2 + 1.f);
          }
        }
      }
      part += __shfl_xor(part, 16);
      part += __shfl_xor(part, 32);
      if (lane < 16) atomicAdd(&colsum[gc], part);
    }
  } else {
    // LDS transpose epilogue: coalesced 32B/lane row stores (per-wave 16x68 f32 region)
    float* smf = (float*)sm;
    float* tw = smf + wid * 16 * 68;  // 8 x 4352 B = 34816 B <= 49152 B
#pragma unroll
    for (int mi = 0; mi < 4; mi++) {
#pragma unroll
      for (int ni = 0; ni < 4; ni++)
#pragma unroll
        for (int r = 0; r < 4; r++)
          tw[(quad * 4 + r) * 68 + ni * 16 + l16] = acc[mi][ni][r];
      int row = lane >> 2, cq = (lane & 3) * 16;
      int gr = m0 + wm * 64 + mi * 16 + row;
      if (gr < M) {
        int gc0 = wn * 64 + cq;
        u16 ob[16];
#pragma unroll
        for (int j = 0; j < 16; j++) ob[j] = f2bf(tw[row * 68 + cq + j] + bias[gc0 + j]);
        *(ushort8*)(Cb + (size_t)gr * 256 + gc0) = *(ushort8*)ob;
        *(ushort8*)(Cb + (size_t)gr * 256 + gc0 + 8) = *(ushort8*)(ob + 8);
      }
    }
  }
}

// ============ k_gemm2_cls: 256-thr 128x128 kernel, ONLY for the N=32 classifier ============
#define BM 128
#define BN 128
#define BK 32

__global__ __launch_bounds__(256) void k_gemm2_cls(
    const u16* __restrict__ A, const u16* __restrict__ A2, const float* __restrict__ attn,
    const u16* __restrict__ Bt, const float* __restrict__ bias,
    float* __restrict__ Cf, int M, int N, int K) {
  __shared__ __align__(16) u16 sm[2][2][BM * BK];  // 32 KiB
  int tid = threadIdx.x;
  int lane = tid & 63, wid = tid >> 6;
  int wm = wid >> 1, wn = wid & 1;
  int quad = lane >> 4, l16 = lane & 15;
  int m0 = blockIdx.x * BM, n0 = 0;

  float a0s = attn[0], a1s = attn[1];

  int sr = lane >> 2;
  int sc = (lane & 3) * 8;
  int ra0 = m0 + wid * 32 + sr;
  int ra1 = ra0 + 16;
  int rb0 = n0 + wid * 32 + sr;
  int rb1 = rb0 + 16;
  if (ra0 >= M) ra0 = M - 1;
  if (ra1 >= M) ra1 = M - 1;
  if (rb0 >= N) rb0 = N - 1;
  if (rb1 >= N) rb1 = N - 1;
  const u16* ga0 = A + (size_t)ra0 * K + sc;
  const u16* ga1 = A + (size_t)ra1 * K + sc;
  const u16* g2a0 = A2 + (size_t)ra0 * K + sc;
  const u16* g2a1 = A2 + (size_t)ra1 * K + sc;
  const u16* gb0 = Bt + (size_t)rb0 * K + sc;
  const u16* gb1 = Bt + (size_t)rb1 * K + sc;
  const int la = wid * 32 * BK;
  const int lb = la + 16 * BK;

  floatx4 acc[4][4];
#pragma unroll
  for (int i = 0; i < 4; i++)
#pragma unroll
    for (int j = 0; j < 4; j++) acc[i][j] = (floatx4){0.f, 0.f, 0.f, 0.f};

  auto stage = [&](int buf, int k0) {
    u16* sa = &sm[buf][0][0];
    u16* sb = &sm[buf][1][0];
    ushort8 u0 = *(const ushort8*)(ga0 + k0);
    ushort8 w0 = *(const ushort8*)(g2a0 + k0);
    ushort8 u1 = *(const ushort8*)(ga1 + k0);
    ushort8 w1 = *(const ushort8*)(g2a1 + k0);
    u16 t0[8], t1[8];
#pragma unroll
    for (int j = 0; j < 8; j++) {
      t0[j] = f2bf(a0s * bf2f(u0[j]) + a1s * bf2f(w0[j]));
      t1[j] = f2bf(a0s * bf2f(u1[j]) + a1s * bf2f(w1[j]));
    }
    *(ushort8*)(sa + la + lane * 8) = *(ushort8*)t0;
    *(ushort8*)(sa + lb + lane * 8) = *(ushort8*)t1;
    gload16(gb0 + k0, sb + la);
    gload16(gb1 + k0, sb + lb);
  };

  stage(0, 0);
  __syncthreads();

  int nk = K / BK;
  for (int t = 0; t < nk; ++t) {
    int cur = t & 1;
    if (t + 1 < nk) stage(cur ^ 1, (t + 1) * BK);
    const u16* Ab = &sm[cur][0][0];
    const u16* Bb = &sm[cur][1][0];
    bf16x8 af[4], bfr[4];
#pragma unroll
    for (int mi = 0; mi < 4; mi++)
      af[mi] = *(const bf16x8*)(Ab + (wm * 64 + mi * 16 + l16) * BK + quad * 8);
#pragma unroll
    for (int ni = 0; ni < 4; ni++)
      bfr[ni] = *(const bf16x8*)(Bb + (wn * 64 + ni * 16 + l16) * BK + quad * 8);
#pragma unroll
    for (int mi = 0; mi < 4; mi++)
#pragma unroll
      for (int ni = 0; ni < 4; ni++)
        acc[mi][ni] = __builtin_amdgcn_mfma_f32_16x16x32_bf16(af[mi], bfr[ni], acc[mi][ni], 0, 0, 0);
    __syncthreads();
  }

#pragma unroll
  for (int ni = 0; ni < 4; ni++) {
    int gc = n0 + wn * 64 + ni * 16 + l16;
    if (gc >= N) continue;
    float bv = bias[gc];
#pragma unroll
    for (int mi = 0; mi < 4; mi++) {
#pragma unroll
      for (int r = 0; r < 4; r++) {
        int gr = m0 + wm * 64 + mi * 16 + quad * 4 + r;
        if (gr < M) Cf[(size_t)gr * N + gc] = acc[mi][ni][r] + bv;
      }
    }
  }
}

// ---------------- per-node attention logits ----------------
__global__ void k_logits(const u16* __restrict__ h, int N,
                         const float* __restrict__ a0, const float* __restrict__ a1,
                         const float* __restrict__ a2, const float* __restrict__ a3,
                         float* __restrict__ o0, float* __restrict__ o1,
                         float* __restrict__ o2, float* __restrict__ o3) {
  int t = blockIdx.x * blockDim.x + threadIdx.x;
  int n = t >> 3, hh = t & 7;
  if (n >= N) return;
  const ushort8* hp = (const ushort8*)(h + (size_t)n * 256 + hh * 32);
  float d0 = 0.f, d1 = 0.f, d2 = 0.f, d3 = 0.f;
#pragma unroll
  for (int q = 0; q < 4; q++) {
    ushort8 v = hp[q];
#pragma unroll
    for (int j = 0; j < 8; j++) {
      float f = bf2f(v[j]);
      int idx = hh * 32 + q * 8 + j;
      d0 += f * a0[idx];
      d1 += f * a1[idx];
      if (a2) d2 += f * a2[idx];
      if (a3) d3 += f * a3[idx];
    }
  }
  o0[t] = d0;
  o1[t] = d1;
  if (o2) o2[t] = d2;
  if (o3) o3[t] = d3;
}

// ------- fused softmax+aggregate: single-pass online, 4-edge pipelined, 1 wave/dst -------
__global__ __launch_bounds__(256) void k_attn_agg(
    const int* __restrict__ rp, const int* __restrict__ esrc,
    const float* __restrict__ als, const float* __restrict__ ald,
    const u16* __restrict__ hsrc, u16* __restrict__ out, int Ndst) {
  int wid = threadIdx.x >> 6, lane = threadIdx.x & 63;
  int n = blockIdx.x * 4 + wid;
  if (n >= Ndst) return;
  int hh = lane >> 3;
  int b = rp[n], e = rp[n + 1];
  float av = ald[n * 8 + hh];
  float m = -1e30f, s = 0.f;
  float a0 = 0.f, a1 = 0.f, a2 = 0.f, a3 = 0.f;
  int i = b;
  for (; i + 3 < e; i += 4) {
    int s0 = esrc[i], s1 = esrc[i + 1], s2 = esrc[i + 2], s3 = esrc[i + 3];
    float x0 = als[s0 * 8 + hh] + av, x1 = als[s1 * 8 + hh] + av;
    float x2 = als[s2 * 8 + hh] + av, x3 = als[s3 * 8 + hh] + av;
    ushort4 v0 = *(const ushort4*)(hsrc + (size_t)s0 * 256 + lane * 4);
    ushort4 v1 = *(const ushort4*)(hsrc + (size_t)s1 * 256 + lane * 4);
    ushort4 v2 = *(const ushort4*)(hsrc + (size_t)s2 * 256 + lane * 4);
    ushort4 v3 = *(const ushort4*)(hsrc + (size_t)s3 * 256 + lane * 4);
    x0 = x0 > 0.f ? x0 : 0.2f * x0;
    x1 = x1 > 0.f ? x1 : 0.2f * x1;
    x2 = x2 > 0.f ? x2 : 0.2f * x2;
    x3 = x3 > 0.f ? x3 : 0.2f * x3;
    float mx = fmaxf(fmaxf(x0, x1), fmaxf(x2, x3));
    if (mx > m) {
      float r = __expf(m - mx);
      s *= r; a0 *= r; a1 *= r; a2 *= r; a3 *= r;
      m = mx;
    }
    float w0 = __expf(x0 - m), w1 = __expf(x1 - m);
    float w2 = __expf(x2 - m), w3 = __expf(x3 - m);
    s += (w0 + w1) + (w2 + w3);
    a0 += w0 * bf2f(v0.x) + w1 * bf2f(v1.x) + w2 * bf2f(v2.x) + w3 * bf2f(v3.x);
    a1 += w0 * bf2f(v0.y) + w1 * bf2f(v1.y) + w2 * bf2f(v2.y) + w3 * bf2f(v3.y);
    a2 += w0 * bf2f(v0.z) + w1 * bf2f(v1.z) + w2 * bf2f(v2.z) + w3 * bf2f(v3.z);
    a3 += w0 * bf2f(v0.w) + w1 * bf2f(v1.w) + w2 * bf2f(v2.w) + w3 * bf2f(v3.w);
  }
  for (; i < e; ++i) {
    int s0 = esrc[i];
    float x0 = als[s0 * 8 + hh] + av;
    ushort4 v0 = *(const ushort4*)(hsrc + (size_t)s0 * 256 + lane * 4);
    x0 = x0 > 0.f ? x0 : 0.2f * x0;
    if (x0 > m) {
      float r = __expf(m - x0);
      s *= r; a0 *= r; a1 *= r; a2 *= r; a3 *= r;
      m = x0;
    }
    float w0 = __expf(x0 - m);
    s += w0;
    a0 += w0 * bf2f(v0.x);
    a1 += w0 * bf2f(v0.y);
    a2 += w0 * bf2f(v0.z);
    a3 += w0 * bf2f(v0.w);
  }
  float inv = 1.f / (s + 1e-16f);
  a0 *= inv; a1 *= inv; a2 *= inv; a3 *= inv;
  ushort4 o;
  o.x = f2bf(a0 > 0.f ? a0 : 0.f);
  o.y = f2bf(a1 > 0.f ? a1 : 0.f);
  o.z = f2bf(a2 > 0.f ? a2 : 0.f);
  o.w = f2bf(a3 > 0.f ? a3 : 0.f);
  *(ushort4*)(out + (size_t)n * 256 + lane * 4) = o;
}

// ---------------- semantic attention scores (K=2) ----------------
__global__ void k_scores(const float* __restrict__ cs0, const float* __restrict__ cs1,
                         const float* __restrict__ q, float invN, float* __restrict__ attn) {
  int lane = threadIdx.x;
  float p0 = 0.f, p1 = 0.f;
  for (int f = lane; f < 256; f += 64) {
    float qv = q[f];
    p0 += qv * cs0[f];
    p1 += qv * cs1[f];
  }
  for (int o = 32; o > 0; o >>= 1) {
    p0 += __shfl_down(p0, o);
    p1 += __shfl_down(p1, o);
  }
  if (lane == 0) {
    float s0 = p0 * invN, s1 = p1 * invN;
    float mx = fmaxf(s0, s1);
    float e0 = __expf(s0 - mx), e1 = __expf(s1 - mx);
    float den = e0 + e1;
    attn[0] = e0 / den;
    attn[1] = e1 / den;
  }
}

extern "C" void kernel_launch(void* const* d_in, const int* in_sizes, int n_in,
                              void* d_out, int out_size, void* d_ws, size_t ws_size,
                              hipStream_t stream) {
  const int NP = 100000, NA = 50000;
  const int EAP = 300000, EPA = 300000, EPP = 500000;

  const float* xP = (const float*)d_in[0];
  const float* xA = (const float*)d_in[1];
  const int* srcAP = (const int*)d_in[2];
  const int* dstAP = (const int*)d_in[3];
  const int* srcPA = (const int*)d_in[4];
  const int* dstPA = (const int*)d_in[5];
  const int* srcPP = (const int*)d_in[6];
  const int* dstPP = (const int*)d_in[7];
  const float *W_P[2], *b_P[2], *W_A[2], *b_A[2];
  const float *asAP[2], *adAP[2], *asPA[2], *adPA[2], *asPP[2], *adPP[2];
  const float *kW[2], *kb[2], *qv[2];
  for (int l = 0; l < 2; ++l) {
    int base = 8 + l * 13;
    W_P[l] = (const float*)d_in[base + 0];
    b_P[l] = (const float*)d_in[base + 1];
    W_A[l] = (const float*)d_in[base + 2];
    b_A[l] = (const float*)d_in[base + 3];
    asAP[l] = (const float*)d_in[base + 4];
    adAP[l] = (const float*)d_in[base + 5];
    asPA[l] = (const float*)d_in[base + 6];
    adPA[l] = (const float*)d_in[base + 7];
    asPP[l] = (const float*)d_in[base + 8];
    adPP[l] = (const float*)d_in[base + 9];
    kW[l] = (const float*)d_in[base + 10];
    kb[l] = (const float*)d_in[base + 11];
    qv[l] = (const float*)d_in[base + 12];
  }
  const float* linW = (const float*)d_in[34];
  const float* linb = (const float*)d_in[35];

  // ---------------- workspace layout ----------------
  char* ws = (char*)d_ws;
  size_t off = 0;
  auto alloc = [&](size_t bytes) -> char* {
    char* p = ws + off;
    off += (bytes + 255) & ~(size_t)255;
    return p;
  };
  u16* P1 = (u16*)alloc((size_t)NP * 256 * 2);
  u16* P2 = (u16*)alloc((size_t)NP * 256 * 2);
  u16* A1 = (u16*)alloc((size_t)NA * 256 * 2);
  u16* A2 = (u16*)alloc((size_t)NA * 256 * 2);
  u16* P3 = (u16*)alloc((size_t)NP * 256 * 2);   // hP1 (dual-GEMM output)
  float* ldAP_P = (float*)alloc((size_t)NP * 8 * 4);
  float* lsPA_P = (float*)alloc((size_t)NP * 8 * 4);
  float* lsPP_P = (float*)alloc((size_t)NP * 8 * 4);
  float* ldPP_P = (float*)alloc((size_t)NP * 8 * 4);
  float* lsAP_A = (float*)alloc((size_t)NA * 8 * 4);
  float* ldPA_A = (float*)alloc((size_t)NA * 8 * 4);
  u16* wtP0 = (u16*)alloc(256 * 512 * 2);
  u16* wtA0 = (u16*)alloc(256 * 256 * 2);
  u16* wtP1 = (u16*)alloc(256 * 256 * 2);
  u16* wtA1 = (u16*)alloc(256 * 256 * 2);
  u16* kwt0 = (u16*)alloc(256 * 256 * 2);
  u16* kwt1 = (u16*)alloc(256 * 256 * 2);
  u16* lwt = (u16*)alloc(32 * 256 * 2);
  int* rpAP = (int*)alloc((NP + 1) * 4);
  int* rpPP = (int*)alloc((NP + 1) * 4);
  int* rpPA = (int*)alloc((NA + 1) * 4);
  int* eiAP = (int*)alloc((size_t)EAP * 4);
  int* eiPP = (int*)alloc((size_t)EPP * 4);
  int* eiPA = (int*)alloc((size_t)EPA * 4);
  int* bsum = (int*)alloc(768 * 4);
  int* bbase = (int*)alloc(768 * 4);
  size_t zbytes = (size_t)(4 * NP + 2 * NA) * 4 + 4 * 256 * 4;
  char* zblock = alloc(zbytes);
  int* cntAP = (int*)zblock;
  int* cntPP = cntAP + NP;
  int* cntPA = cntPP + NP;
  int* curAP = cntPA + NA;
  int* curPP = curAP + NP;
  int* curPA = curPP + NP;
  float* cs = (float*)(curPA + NA);  // 4 x 256
  float* attnBuf = (float*)alloc(256);

  // Overlay views (no extra workspace):
  u16* HP = A1;                       // [NP][256] bf16 spans exactly A1|A2
  u16* hA0 = P2;                      // [NA][256] bf16 = first half of P2
  u16* P2b = P2 + (size_t)NA * 256;   // [NA][256] bf16 = second half of P2 (newA)

  (void)hipMemsetAsync((void*)zblock, 0, zbytes, stream);

  // weight transposes (f32 -> bf16)
  k_transpose<<<CEILDIV(512 * 256, 256), 256, 0, stream>>>(W_P[0], wtP0, 512, 256);
  k_transpose<<<CEILDIV(256 * 256, 256), 256, 0, stream>>>(W_A[0], wtA0, 256, 256);
  k_transpose<<<CEILDIV(256 * 256, 256), 256, 0, stream>>>(W_P[1], wtP1, 256, 256);
  k_transpose<<<CEILDIV(256 * 256, 256), 256, 0, stream>>>(W_A[1], wtA1, 256, 256);
  k_transpose<<<CEILDIV(256 * 256, 256), 256, 0, stream>>>(kW[0], kwt0, 256, 256);
  k_transpose<<<CEILDIV(256 * 256, 256), 256, 0, stream>>>(kW[1], kwt1, 256, 256);
  k_transpose<<<CEILDIV(256 * 32, 256), 256, 0, stream>>>(linW, lwt, 256, 32);

  // CSR build (by dst), payload = src node id; shared by both layers
  k_hist3<<<CEILDIV(EAP + EPP + EPA, 256), 256, 0, stream>>>(
      dstAP, EAP, cntAP, dstPP, EPP, cntPP, dstPA, EPA, cntPA);
  k_scan_a<<<245, 256, 0, stream>>>(cntAP, cntPP, cntPA, bsum);
  k_scan_b<<<1, 256, 0, stream>>>(bsum, bbase, rpAP, rpPP, rpPA);
  k_scan_c<<<245, 256, 0, stream>>>(cntAP, cntPP, cntPA, bbase, rpAP, rpPP, rpPA);
  k_scatter3<<<CEILDIV(EAP + EPP + EPA, 256), 256, 0, stream>>>(
      dstAP, srcAP, EAP, rpAP, curAP, eiAP,
      dstPP, srcPP, EPP, rpPP, curPP, eiPP,
      dstPA, srcPA, EPA, rpPA, curPA, eiPA);

  int gP = CEILDIV(NP, G3_BM), gA = CEILDIV(NA, G3_BM);

  // =================== Layer 0 ===================
  // projections read f32 inputs directly (fused convert in staging)
  k_gemm3<2, 0><<<gP, 512, 0, stream>>>(xP, nullptr, nullptr, wtP0, b_P[0], HP, nullptr, NP, 512);
  k_gemm3<2, 0><<<gA, 512, 0, stream>>>(xA, nullptr, nullptr, wtA0, b_A[0], hA0, nullptr, NA, 256);

  k_logits<<<CEILDIV(NP * 8, 256), 256, 0, stream>>>(
      HP, NP, adAP[0], asPA[0], asPP[0], adPP[0], ldAP_P, lsPA_P, lsPP_P, ldPP_P);
  k_logits<<<CEILDIV(NA * 8, 256), 256, 0, stream>>>(
      hA0, NA, asAP[0], adPA[0], nullptr, nullptr, lsAP_A, ldPA_A, nullptr, nullptr);
  // PP: papers->papers (src hP=HP -> oPP=P1)
  k_attn_agg<<<CEILDIV(NP, 4), 256, 0, stream>>>(rpPP, eiPP, lsPP_P, ldPP_P, HP, P1, NP);
  // PA: papers->authors (src hP=HP -> oPA=newA=P2b)
  k_attn_agg<<<CEILDIV(NA, 4), 256, 0, stream>>>(rpPA, eiPA, lsPA_P, ldPA_A, HP, P2b, NA);
  // AP: authors->papers (src hA=hA0 -> oAP=HP; hP dead now)
  k_attn_agg<<<CEILDIV(NP, 4), 256, 0, stream>>>(rpAP, eiAP, lsAP_A, ldAP_P, hA0, HP, NP);
  // semantic over {oAP=HP, oPP=P1}
  k_gemm3<0, 1><<<gP, 512, 0, stream>>>(HP, nullptr, nullptr, kwt0, kb[0], nullptr, cs, NP, 256);
  k_gemm3<0, 1><<<gP, 512, 0, stream>>>(P1, nullptr, nullptr, kwt0, kb[0], nullptr, cs + 256, NP, 256);
  k_scores<<<1, 64, 0, stream>>>(cs, cs + 256, qv[0], 1.0f / NP, attnBuf);
  // fused semantic-combine + layer-1 paper projection: hP1 = (a0*oAP + a1*oPP) @ W_P1 + b_P1
  k_gemm3<1, 0><<<gP, 512, 0, stream>>>(HP, P1, attnBuf, wtP1, b_P[1], P3, nullptr, NP, 256);

  // =================== Layer 1 ===================
  k_gemm3<0, 0><<<gA, 512, 0, stream>>>(P2b, nullptr, nullptr, wtA1, b_A[1], hA0, nullptr, NA, 256);
  k_logits<<<CEILDIV(NP * 8, 256), 256, 0, stream>>>(
      P3, NP, adAP[1], asPA[1], asPP[1], adPP[1], ldAP_P, lsPA_P, lsPP_P, ldPP_P);
  k_logits<<<CEILDIV(NA * 8, 256), 256, 0, stream>>>(
      hA0, NA, asAP[1], adPA[1], nullptr, nullptr, lsAP_A, ldPA_A, nullptr, nullptr);
  // PP: src hP1=P3 -> oPP1=P1
  k_attn_agg<<<CEILDIV(NP, 4), 256, 0, stream>>>(rpPP, eiPP, lsPP_P, ldPP_P, P3, P1, NP);
  // AP: src hA1=hA0 -> oAP1=HP
  k_attn_agg<<<CEILDIV(NP, 4), 256, 0, stream>>>(rpAP, eiAP, lsAP_A, ldAP_P, hA0, HP, NP);
  // semantic over {oAP1=HP, oPP1=P1}
  k_gemm3<0, 1><<<gP, 512, 0, stream>>>(HP, nullptr, nullptr, kwt1, kb[1], nullptr, cs + 512, NP, 256);
  k_gemm3<0, 1><<<gP, 512, 0, stream>>>(P1, nullptr, nullptr, kwt1, kb[1], nullptr, cs + 768, NP, 256);
  k_scores<<<1, 64, 0, stream>>>(cs + 512, cs + 768, qv[1], 1.0f / NP, attnBuf + 2);

  // classifier fused with semantic combine: d_out = (a0*oAP1 + a1*oPP1) @ linW + linb
  k_gemm2_cls<<<CEILDIV(NP, BM), 256, 0, stream>>>(
      HP, P1, attnBuf + 2, lwt, linb, (float*)d_out, NP, 32, 256);
}

// Round 9
// 1148.839 us; speedup vs baseline: 2.0875x; 1.1922x over previous
//
#include <hip/hip_runtime.h>
#include <math.h>

typedef unsigned short u16;
typedef u16 ushort8 __attribute__((ext_vector_type(8)));
typedef __bf16 bf16x8 __attribute__((ext_vector_type(8)));
typedef float floatx4 __attribute__((ext_vector_type(4)));

__device__ __forceinline__ float bf2f(u16 u) {
  union { unsigned int i; float f; } v; v.i = ((unsigned int)u) << 16; return v.f;
}
__device__ __forceinline__ u16 f2bf(float f) {
  union { float f; unsigned int i; } v; v.f = f;
  return (u16)((v.i + 0x7fffu + ((v.i >> 16) & 1u)) >> 16);
}

#define CEILDIV(a, b) (((a) + (b) - 1) / (b))

// ---------------- async global->LDS, 16 B per lane ----------------
typedef const __attribute__((address_space(1))) unsigned int ga_u32;
typedef __attribute__((address_space(3))) unsigned int lds_u32;
__device__ __forceinline__ void gload16(const u16* g, u16* l) {
  __builtin_amdgcn_global_load_lds((ga_u32*)g, (lds_u32*)l, 16, 0, 0);
}

// ------- merged weight transposes: 7 segments, W[K][N] f32 -> Wt[N][K] bf16 -------
__global__ void k_transpose7(
    const float* __restrict__ W0, u16* __restrict__ T0,
    const float* __restrict__ W1, u16* __restrict__ T1,
    const float* __restrict__ W2, u16* __restrict__ T2,
    const float* __restrict__ W3, u16* __restrict__ T3,
    const float* __restrict__ W4, u16* __restrict__ T4,
    const float* __restrict__ W5, u16* __restrict__ T5,
    const float* __restrict__ W6, u16* __restrict__ T6) {
  int t = blockIdx.x * blockDim.x + threadIdx.x;
  const float* W; u16* T; int K, N, u;
  if (t < 131072) { W = W0; T = T0; K = 512; N = 256; u = t; }
  else if (t < 196608) { W = W1; T = T1; K = 256; N = 256; u = t - 131072; }
  else if (t < 262144) { W = W2; T = T2; K = 256; N = 256; u = t - 196608; }
  else if (t < 327680) { W = W3; T = T3; K = 256; N = 256; u = t - 262144; }
  else if (t < 393216) { W = W4; T = T4; K = 256; N = 256; u = t - 327680; }
  else if (t < 458752) { W = W5; T = T5; K = 256; N = 256; u = t - 393216; }
  else if (t < 466944) { W = W6; T = T6; K = 256; N = 32; u = t - 458752; }
  else return;
  int n = u / K, k = u - n * K;
  T[u] = f2bf(W[k * N + n]);
}

// ---------------- CSR build: fused 3-segment hist / scatter ----------------
__global__ void k_hist3(const int* __restrict__ d0, int E0, int* __restrict__ c0,
                        const int* __restrict__ d1, int E1, int* __restrict__ c1,
                        const int* __restrict__ d2, int E2, int* __restrict__ c2) {
  int t = blockIdx.x * blockDim.x + threadIdx.x;
  if (t < E0) atomicAdd(&c0[d0[t]], 1);
  else if (t < E0 + E1) atomicAdd(&c1[d1[t - E0]], 1);
  else if (t < E0 + E1 + E2) atomicAdd(&c2[d2[t - E0 - E1]], 1);
}

__global__ void k_scatter3(
    const int* __restrict__ d0, const int* __restrict__ s0v, int E0,
    const int* __restrict__ rp0, int* __restrict__ cur0, int* __restrict__ es0,
    const int* __restrict__ d1, const int* __restrict__ s1v, int E1,
    const int* __restrict__ rp1, int* __restrict__ cur1, int* __restrict__ es1,
    const int* __restrict__ d2, const int* __restrict__ s2v, int E2,
    const int* __restrict__ rp2, int* __restrict__ cur2, int* __restrict__ es2) {
  int t = blockIdx.x * blockDim.x + threadIdx.x;
  if (t < E0) {
    int d = d0[t];
    int p = atomicAdd(&cur0[d], 1);
    es0[rp0[d] + p] = s0v[t];
  } else if (t < E0 + E1) {
    int u = t - E0;
    int d = d1[u];
    int p = atomicAdd(&cur1[d], 1);
    es1[rp1[d] + p] = s1v[u];
  } else if (t < E0 + E1 + E2) {
    int u = t - E0 - E1;
    int d = d2[u];
    int p = atomicAdd(&cur2[d], 1);
    es2[rp2[d] + p] = s2v[u];
  }
}

// ---- two-level exclusive scan, fused over 3 segments (AP:100k, PP:100k, PA:50k) ----
__device__ __forceinline__ void seg_map(int b, int& seg, int& bs, int& n) {
  if (b < 98) { seg = 0; bs = b; n = 100000; }
  else if (b < 196) { seg = 1; bs = b - 98; n = 100000; }
  else { seg = 2; bs = b - 196; n = 50000; }
}

__global__ __launch_bounds__(256) void k_scan_a(
    const int* __restrict__ c0, const int* __restrict__ c1, const int* __restrict__ c2,
    int* __restrict__ bsum) {
  int seg, bs, n;
  seg_map(blockIdx.x, seg, bs, n);
  const int* cnt = seg == 0 ? c0 : (seg == 1 ? c1 : c2);
  int t = threadIdx.x;
  int base = bs * 1024 + t * 4;
  int s = 0;
#pragma unroll
  for (int j = 0; j < 4; j++) { int i = base + j; if (i < n) s += cnt[i]; }
#pragma unroll
  for (int o = 1; o < 64; o <<= 1) s += __shfl_xor(s, o);
  __shared__ int wt[4];
  int lane = t & 63, w = t >> 6;
  if (lane == 0) wt[w] = s;
  __syncthreads();
  if (t == 0) bsum[seg * 256 + bs] = wt[0] + wt[1] + wt[2] + wt[3];
}

__global__ __launch_bounds__(256) void k_scan_b(
    const int* __restrict__ bsum, int* __restrict__ bbase,
    int* __restrict__ rp0, int* __restrict__ rp1, int* __restrict__ rp2) {
  __shared__ int sm[256];
  int t = threadIdx.x;
  for (int seg = 0; seg < 3; ++seg) {
    int nb = (seg == 2) ? 49 : 98;
    int n = (seg == 2) ? 50000 : 100000;
    int v = (t < nb) ? bsum[seg * 256 + t] : 0;
    sm[t] = v;
    __syncthreads();
    for (int o = 1; o < 256; o <<= 1) {
      int u = (t >= o) ? sm[t - o] : 0;
      __syncthreads();
      sm[t] += u;
      __syncthreads();
    }
    if (t < nb) bbase[seg * 256 + t] = sm[t] - v;
    if (t == 255) {
      int* rp = seg == 0 ? rp0 : (seg == 1 ? rp1 : rp2);
      rp[n] = sm[255];
    }
    __syncthreads();
  }
}

__global__ __launch_bounds__(256) void k_scan_c(
    const int* __restrict__ c0, const int* __restrict__ c1, const int* __restrict__ c2,
    const int* __restrict__ bbase,
    int* __restrict__ rp0, int* __restrict__ rp1, int* __restrict__ rp2) {
  int seg, bs, n;
  seg_map(blockIdx.x, seg, bs, n);
  const int* cnt = seg == 0 ? c0 : (seg == 1 ? c1 : c2);
  int* rp = seg == 0 ? rp0 : (seg == 1 ? rp1 : rp2);
  int t = threadIdx.x;
  int base = bs * 1024 + t * 4;
  int c[4];
  int s = 0;
#pragma unroll
  for (int j = 0; j < 4; j++) { int i = base + j; c[j] = (i < n) ? cnt[i] : 0; s += c[j]; }
  int lane = t & 63, w = t >> 6;
  int incl = s;
#pragma unroll
  for (int o = 1; o < 64; o <<= 1) { int u = __shfl_up(incl, o); if (lane >= o) incl += u; }
  __shared__ int wt[4];
  if (lane == 63) wt[w] = incl;
  __syncthreads();
  int wb = 0;
#pragma unroll
  for (int j = 0; j < 4; j++) if (j < w) wb += wt[j];
  int thr = bbase[seg * 256 + bs] + wb + incl - s;
#pragma unroll
  for (int j = 0; j < 4; j++) { int i = base + j; if (i < n) rp[i] = thr; thr += c[j]; }
}

// ================= k_gemm3: full-width N=256 block, 512 thr / 8 waves =================
// SRC 0: bf16 A via global_load_lds. SRC 1: dual bf16 blend a0*A+a1*A2. SRC 2: f32 A (fused cvt).
// MODE 0: store bf16 Cb (+fused per-head logits when NL>0). MODE 1: fast-tanh colsum atomic.
// PAIR 1 (MODE 1 only): grid = 2*gP; second half processes (A2 -> colsum+256).
#define G3_BM 128
#define G3_BN 256
#define G3_BK 32

template <int SRC, int MODE, int NL, int PAIR>
__global__ __launch_bounds__(512, 4) void k_gemm3(
    const void* __restrict__ Av, const u16* __restrict__ A2, const float* __restrict__ attn,
    const u16* __restrict__ Bt, const float* __restrict__ bias,
    u16* __restrict__ Cb, float* __restrict__ colsum, int M, int K,
    const float* __restrict__ av0, const float* __restrict__ av1,
    const float* __restrict__ av2, const float* __restrict__ av3,
    float* __restrict__ lo0, float* __restrict__ lo1,
    float* __restrict__ lo2, float* __restrict__ lo3) {
  __shared__ __align__(16) u16 sm[2][(G3_BM + G3_BN) * G3_BK];  // 48 KiB
  int bid = blockIdx.x;
  if (PAIR) {
    int half = (int)gridDim.x >> 1;
    if (bid >= half) { bid -= half; Av = (const void*)A2; colsum += 256; }
  }
  int tid = threadIdx.x;
  int lane = tid & 63, wid = tid >> 6;   // 8 waves
  int wm = wid >> 2, wn = wid & 3;       // 2 x 4 wave grid, 64x64 per wave
  int quad = lane >> 4, l16 = lane & 15;
  int m0 = bid * G3_BM;

  float a0s = 0.f, a1s = 0.f;
  if (SRC == 1) { a0s = attn[0]; a1s = attn[1]; }

  int gr_ = tid >> 2;                 // row within chunk (0..127)
  int gc_ = (tid & 3) * 8;            // u16 col (0/8/16/24)
  int arow = m0 + gr_; if (arow >= M) arow = M - 1;
  const u16* gaB = (SRC != 2) ? (const u16*)Av + (size_t)arow * K + gc_ : nullptr;
  const u16* ga2 = (SRC == 1) ? A2 + (size_t)arow * K + gc_ : nullptr;
  const float* gaF = (SRC == 2) ? (const float*)Av + (size_t)arow * K + gc_ : nullptr;
  const u16* gb0 = Bt + (size_t)gr_ * K + gc_;          // B rows 0..127
  const u16* gb1 = Bt + (size_t)(128 + gr_) * K + gc_;  // B rows 128..255
  const int laA = wid * 512;
  const int laB0 = 4096 + wid * 512;
  const int laB1 = 8192 + wid * 512;

  floatx4 acc[4][4];
#pragma unroll
  for (int i = 0; i < 4; i++)
#pragma unroll
    for (int j = 0; j < 4; j++) acc[i][j] = (floatx4){0.f, 0.f, 0.f, 0.f};

  auto stage = [&](int buf, int k0) {
    u16* sa = sm[buf];
    if (SRC == 0) {
      gload16(gaB + k0, sa + laA);
    } else if (SRC == 2) {
      const floatx4* p = (const floatx4*)(gaF + k0);
      floatx4 v0 = p[0], v1 = p[1];
      u16 t[8];
#pragma unroll
      for (int j = 0; j < 4; j++) { t[j] = f2bf(v0[j]); t[4 + j] = f2bf(v1[j]); }
      *(ushort8*)(sa + laA + (lane << 3)) = *(ushort8*)t;
    } else {
      ushort8 u = *(const ushort8*)(gaB + k0);
      ushort8 w = *(const ushort8*)(ga2 + k0);
      u16 t[8];
#pragma unroll
      for (int j = 0; j < 8; j++) t[j] = f2bf(a0s * bf2f(u[j]) + a1s * bf2f(w[j]));
      *(ushort8*)(sa + laA + (lane << 3)) = *(ushort8*)t;
    }
    gload16(gb0 + k0, sa + laB0);
    gload16(gb1 + k0, sa + laB1);
  };

  stage(0, 0);
  __syncthreads();

  int nk = K / G3_BK;
  for (int t = 0; t < nk; ++t) {
    int cur = t & 1;
    if (t + 1 < nk) stage(cur ^ 1, (t + 1) * G3_BK);
    const u16* Ab = sm[cur];
    const u16* Bb = sm[cur] + G3_BM * G3_BK;
    bf16x8 af[4], bfr[4];
#pragma unroll
    for (int mi = 0; mi < 4; mi++)
      af[mi] = *(const bf16x8*)(Ab + (wm * 64 + mi * 16 + l16) * G3_BK + quad * 8);
#pragma unroll
    for (int ni = 0; ni < 4; ni++)
      bfr[ni] = *(const bf16x8*)(Bb + (wn * 64 + ni * 16 + l16) * G3_BK + quad * 8);
#pragma unroll
    for (int mi = 0; mi < 4; mi++)
#pragma unroll
      for (int ni = 0; ni < 4; ni++)
        acc[mi][ni] = __builtin_amdgcn_mfma_f32_16x16x32_bf16(af[mi], bfr[ni], acc[mi][ni], 0, 0, 0);
    __syncthreads();
  }

  if (MODE == 1) {
#pragma unroll
    for (int ni = 0; ni < 4; ni++) {
      int gc = wn * 64 + ni * 16 + l16;
      float bv = bias[gc];
      float part = 0.f;
#pragma unroll
      for (int mi = 0; mi < 4; mi++) {
#pragma unroll
        for (int r = 0; r < 4; r++) {
          int gr = m0 + wm * 64 + mi * 16 + quad * 4 + r;
          if (gr < M) {
            float v = acc[mi][ni][r] + bv;
            float e2 = __expf(2.f * v);           // fast tanh = 1 - 2/(e^{2v}+1)
            part += 1.f - 2.f / (e2 + 1.f);
          }
        }
      }
      part += __shfl_xor(part, 16);
      part += __shfl_xor(part, 32);
      if (lane < 16) atomicAdd(&colsum[gc], part);
    }
  } else {
    // LDS transpose epilogue + optional fused per-head logits.
    // Wave wn owns cols [wn*64, wn*64+64) == heads {2wn, 2wn+1} exactly.
    float* smf = (float*)sm;
    float* tw = smf + wid * 16 * 68;
#pragma unroll
    for (int mi = 0; mi < 4; mi++) {
#pragma unroll
      for (int ni = 0; ni < 4; ni++)
#pragma unroll
        for (int r = 0; r < 4; r++)
          tw[(quad * 4 + r) * 68 + ni * 16 + l16] = acc[mi][ni][r];
      int row = lane >> 2, cq = (lane & 3) * 16;
      int gr = m0 + wm * 64 + mi * 16 + row;
      int gc0 = wn * 64 + cq;
      u16 ob[16];
      float p0 = 0.f, p1 = 0.f, p2 = 0.f, p3 = 0.f;
#pragma unroll
      for (int j = 0; j < 16; j++) {
        float v = tw[row * 68 + cq + j] + bias[gc0 + j];
        ob[j] = f2bf(v);
        if (NL > 0) {
          int col = gc0 + j;
          p0 += v * av0[col];
          p1 += v * av1[col];
          if (NL > 2) { p2 += v * av2[col]; p3 += v * av3[col]; }
        }
      }
      if (gr < M) {
        *(ushort8*)(Cb + (size_t)gr * 256 + gc0) = *(ushort8*)ob;
        *(ushort8*)(Cb + (size_t)gr * 256 + gc0 + 8) = *(ushort8*)(ob + 8);
      }
      if (NL > 0) {
        p0 += __shfl_xor(p0, 1);
        p1 += __shfl_xor(p1, 1);
        if (NL > 2) { p2 += __shfl_xor(p2, 1); p3 += __shfl_xor(p3, 1); }
        if ((lane & 1) == 0 && gr < M) {
          int hd = wn * 2 + ((lane & 3) >> 1);
          lo0[gr * 8 + hd] = p0;
          lo1[gr * 8 + hd] = p1;
          if (NL > 2) { lo2[gr * 8 + hd] = p2; lo3[gr * 8 + hd] = p3; }
        }
      }
    }
  }
}

// ============ k_gemm2_cls: 256-thr 128x128 kernel, ONLY for the N=32 classifier ============
#define BM 128
#define BK 32

__global__ __launch_bounds__(256) void k_gemm2_cls(
    const u16* __restrict__ A, const u16* __restrict__ A2, const float* __restrict__ attn,
    const u16* __restrict__ Bt, const float* __restrict__ bias,
    float* __restrict__ Cf, int M, int N, int K) {
  __shared__ __align__(16) u16 sm[2][2][BM * BK];  // 32 KiB
  int tid = threadIdx.x;
  int lane = tid & 63, wid = tid >> 6;
  int wm = wid >> 1, wn = wid & 1;
  int quad = lane >> 4, l16 = lane & 15;
  int m0 = blockIdx.x * BM, n0 = 0;

  float a0s = attn[0], a1s = attn[1];

  int sr = lane >> 2;
  int sc = (lane & 3) * 8;
  int ra0 = m0 + wid * 32 + sr;
  int ra1 = ra0 + 16;
  int rb0 = n0 + wid * 32 + sr;
  int rb1 = rb0 + 16;
  if (ra0 >= M) ra0 = M - 1;
  if (ra1 >= M) ra1 = M - 1;
  if (rb0 >= N) rb0 = N - 1;
  if (rb1 >= N) rb1 = N - 1;
  const u16* ga0 = A + (size_t)ra0 * K + sc;
  const u16* ga1 = A + (size_t)ra1 * K + sc;
  const u16* g2a0 = A2 + (size_t)ra0 * K + sc;
  const u16* g2a1 = A2 + (size_t)ra1 * K + sc;
  const u16* gb0 = Bt + (size_t)rb0 * K + sc;
  const u16* gb1 = Bt + (size_t)rb1 * K + sc;
  const int la = wid * 32 * BK;
  const int lb = la + 16 * BK;

  floatx4 acc[4][4];
#pragma unroll
  for (int i = 0; i < 4; i++)
#pragma unroll
    for (int j = 0; j < 4; j++) acc[i][j] = (floatx4){0.f, 0.f, 0.f, 0.f};

  auto stage = [&](int buf, int k0) {
    u16* sa = &sm[buf][0][0];
    u16* sb = &sm[buf][1][0];
    ushort8 u0 = *(const ushort8*)(ga0 + k0);
    ushort8 w0 = *(const ushort8*)(g2a0 + k0);
    ushort8 u1 = *(const ushort8*)(ga1 + k0);
    ushort8 w1 = *(const ushort8*)(g2a1 + k0);
    u16 t0[8], t1[8];
#pragma unroll
    for (int j = 0; j < 8; j++) {
      t0[j] = f2bf(a0s * bf2f(u0[j]) + a1s * bf2f(w0[j]));
      t1[j] = f2bf(a0s * bf2f(u1[j]) + a1s * bf2f(w1[j]));
    }
    *(ushort8*)(sa + la + lane * 8) = *(ushort8*)t0;
    *(ushort8*)(sa + lb + lane * 8) = *(ushort8*)t1;
    gload16(gb0 + k0, sb + la);
    gload16(gb1 + k0, sb + lb);
  };

  stage(0, 0);
  __syncthreads();

  int nk = K / BK;
  for (int t = 0; t < nk; ++t) {
    int cur = t & 1;
    if (t + 1 < nk) stage(cur ^ 1, (t + 1) * BK);
    const u16* Ab = &sm[cur][0][0];
    const u16* Bb = &sm[cur][1][0];
    bf16x8 af[4], bfr[4];
#pragma unroll
    for (int mi = 0; mi < 4; mi++)
      af[mi] = *(const bf16x8*)(Ab + (wm * 64 + mi * 16 + l16) * BK + quad * 8);
#pragma unroll
    for (int ni = 0; ni < 4; ni++)
      bfr[ni] = *(const bf16x8*)(Bb + (wn * 64 + ni * 16 + l16) * BK + quad * 8);
#pragma unroll
    for (int mi = 0; mi < 4; mi++)
#pragma unroll
      for (int ni = 0; ni < 4; ni++)
        acc[mi][ni] = __builtin_amdgcn_mfma_f32_16x16x32_bf16(af[mi], bfr[ni], acc[mi][ni], 0, 0, 0);
    __syncthreads();
  }

#pragma unroll
  for (int ni = 0; ni < 4; ni++) {
    int gc = n0 + wn * 64 + ni * 16 + l16;
    if (gc >= N) continue;
    float bv = bias[gc];
#pragma unroll
    for (int mi = 0; mi < 4; mi++) {
#pragma unroll
      for (int r = 0; r < 4; r++) {
        int gr = m0 + wm * 64 + mi * 16 + quad * 4 + r;
        if (gr < M) Cf[(size_t)gr * N + gc] = acc[mi][ni][r] + bv;
      }
    }
  }
}

// ------- merged attn: up to 3 segments, single-pass online softmax-agg, 1 wave/dst -------
__global__ __launch_bounds__(256) void k_attn3(
    int nb0, int nb1,
    const int* __restrict__ rp0, const int* __restrict__ es0, const float* __restrict__ als0,
    const float* __restrict__ ald0, const u16* __restrict__ h0, u16* __restrict__ out0, int N0,
    const int* __restrict__ rp1, const int* __restrict__ es1, const float* __restrict__ als1,
    const float* __restrict__ ald1, const u16* __restrict__ h1, u16* __restrict__ out1, int N1,
    const int* __restrict__ rp2, const int* __restrict__ es2, const float* __restrict__ als2,
    const float* __restrict__ ald2, const u16* __restrict__ h2, u16* __restrict__ out2, int N2) {
  int bid = blockIdx.x;
  const int* rp; const int* esrc; const float* als; const float* ald;
  const u16* hsrc; u16* out; int Ndst;
  if (bid < nb0) { rp = rp0; esrc = es0; als = als0; ald = ald0; hsrc = h0; out = out0; Ndst = N0; }
  else if (bid < nb0 + nb1) {
    bid -= nb0;
    rp = rp1; esrc = es1; als = als1; ald = ald1; hsrc = h1; out = out1; Ndst = N1;
  } else {
    bid -= nb0 + nb1;
    rp = rp2; esrc = es2; als = als2; ald = ald2; hsrc = h2; out = out2; Ndst = N2;
  }
  int wid = threadIdx.x >> 6, lane = threadIdx.x & 63;
  int n = bid * 4 + wid;
  if (n >= Ndst) return;
  int hh = lane >> 3;
  int b = rp[n], e = rp[n + 1];
  float av = ald[n * 8 + hh];
  float m = -1e30f, s = 0.f;
  float a0 = 0.f, a1 = 0.f, a2 = 0.f, a3 = 0.f;
  int i = b;
  for (; i + 3 < e; i += 4) {
    int s0 = esrc[i], s1 = esrc[i + 1], s2 = esrc[i + 2], s3 = esrc[i + 3];
    float x0 = als[s0 * 8 + hh] + av, x1 = als[s1 * 8 + hh] + av;
    float x2 = als[s2 * 8 + hh] + av, x3 = als[s3 * 8 + hh] + av;
    ushort4 v0 = *(const ushort4*)(hsrc + (size_t)s0 * 256 + lane * 4);
    ushort4 v1 = *(const ushort4*)(hsrc + (size_t)s1 * 256 + lane * 4);
    ushort4 v2 = *(const ushort4*)(hsrc + (size_t)s2 * 256 + lane * 4);
    ushort4 v3 = *(const ushort4*)(hsrc + (size_t)s3 * 256 + lane * 4);
    x0 = x0 > 0.f ? x0 : 0.2f * x0;
    x1 = x1 > 0.f ? x1 : 0.2f * x1;
    x2 = x2 > 0.f ? x2 : 0.2f * x2;
    x3 = x3 > 0.f ? x3 : 0.2f * x3;
    float mx = fmaxf(fmaxf(x0, x1), fmaxf(x2, x3));
    if (mx > m) {
      float r = __expf(m - mx);
      s *= r; a0 *= r; a1 *= r; a2 *= r; a3 *= r;
      m = mx;
    }
    float w0 = __expf(x0 - m), w1 = __expf(x1 - m);
    float w2 = __expf(x2 - m), w3 = __expf(x3 - m);
    s += (w0 + w1) + (w2 + w3);
    a0 += w0 * bf2f(v0.x) + w1 * bf2f(v1.x) + w2 * bf2f(v2.x) + w3 * bf2f(v3.x);
    a1 += w0 * bf2f(v0.y) + w1 * bf2f(v1.y) + w2 * bf2f(v2.y) + w3 * bf2f(v3.y);
    a2 += w0 * bf2f(v0.z) + w1 * bf2f(v1.z) + w2 * bf2f(v2.z) + w3 * bf2f(v3.z);
    a3 += w0 * bf2f(v0.w) + w1 * bf2f(v1.w) + w2 * bf2f(v2.w) + w3 * bf2f(v3.w);
  }
  for (; i < e; ++i) {
    int s0 = esrc[i];
    float x0 = als[s0 * 8 + hh] + av;
    ushort4 v0 = *(const ushort4*)(hsrc + (size_t)s0 * 256 + lane * 4);
    x0 = x0 > 0.f ? x0 : 0.2f * x0;
    if (x0 > m) {
      float r = __expf(m - x0);
      s *= r; a0 *= r; a1 *= r; a2 *= r; a3 *= r;
      m = x0;
    }
    float w0 = __expf(x0 - m);
    s += w0;
    a0 += w0 * bf2f(v0.x);
    a1 += w0 * bf2f(v0.y);
    a2 += w0 * bf2f(v0.z);
    a3 += w0 * bf2f(v0.w);
  }
  float inv = 1.f / (s + 1e-16f);
  a0 *= inv; a1 *= inv; a2 *= inv; a3 *= inv;
  ushort4 o;
  o.x = f2bf(a0 > 0.f ? a0 : 0.f);
  o.y = f2bf(a1 > 0.f ? a1 : 0.f);
  o.z = f2bf(a2 > 0.f ? a2 : 0.f);
  o.w = f2bf(a3 > 0.f ? a3 : 0.f);
  *(ushort4*)(out + (size_t)n * 256 + lane * 4) = o;
}

// ---------------- semantic attention scores (K=2) ----------------
__global__ void k_scores(const float* __restrict__ cs0, const float* __restrict__ cs1,
                         const float* __restrict__ q, float invN, float* __restrict__ attn) {
  int lane = threadIdx.x;
  float p0 = 0.f, p1 = 0.f;
  for (int f = lane; f < 256; f += 64) {
    float qv = q[f];
    p0 += qv * cs0[f];
    p1 += qv * cs1[f];
  }
  for (int o = 32; o > 0; o >>= 1) {
    p0 += __shfl_down(p0, o);
    p1 += __shfl_down(p1, o);
  }
  if (lane == 0) {
    float s0 = p0 * invN, s1 = p1 * invN;
    float mx = fmaxf(s0, s1);
    float e0 = __expf(s0 - mx), e1 = __expf(s1 - mx);
    float den = e0 + e1;
    attn[0] = e0 / den;
    attn[1] = e1 / den;
  }
}

extern "C" void kernel_launch(void* const* d_in, const int* in_sizes, int n_in,
                              void* d_out, int out_size, void* d_ws, size_t ws_size,
                              hipStream_t stream) {
  const int NP = 100000, NA = 50000;
  const int EAP = 300000, EPA = 300000, EPP = 500000;

  const float* xP = (const float*)d_in[0];
  const float* xA = (const float*)d_in[1];
  const int* srcAP = (const int*)d_in[2];
  const int* dstAP = (const int*)d_in[3];
  const int* srcPA = (const int*)d_in[4];
  const int* dstPA = (const int*)d_in[5];
  const int* srcPP = (const int*)d_in[6];
  const int* dstPP = (const int*)d_in[7];
  const float *W_P[2], *b_P[2], *W_A[2], *b_A[2];
  const float *asAP[2], *adAP[2], *asPA[2], *adPA[2], *asPP[2], *adPP[2];
  const float *kW[2], *kb[2], *qv[2];
  for (int l = 0; l < 2; ++l) {
    int base = 8 + l * 13;
    W_P[l] = (const float*)d_in[base + 0];
    b_P[l] = (const float*)d_in[base + 1];
    W_A[l] = (const float*)d_in[base + 2];
    b_A[l] = (const float*)d_in[base + 3];
    asAP[l] = (const float*)d_in[base + 4];
    adAP[l] = (const float*)d_in[base + 5];
    asPA[l] = (const float*)d_in[base + 6];
    adPA[l] = (const float*)d_in[base + 7];
    asPP[l] = (const float*)d_in[base + 8];
    adPP[l] = (const float*)d_in[base + 9];
    kW[l] = (const float*)d_in[base + 10];
    kb[l] = (const float*)d_in[base + 11];
    qv[l] = (const float*)d_in[base + 12];
  }
  const float* linW = (const float*)d_in[34];
  const float* linb = (const float*)d_in[35];

  // ---------------- workspace layout ----------------
  char* ws = (char*)d_ws;
  size_t off = 0;
  auto alloc = [&](size_t bytes) -> char* {
    char* p = ws + off;
    off += (bytes + 255) & ~(size_t)255;
    return p;
  };
  u16* P1 = (u16*)alloc((size_t)NP * 256 * 2);
  u16* P2 = (u16*)alloc((size_t)NP * 256 * 2);
  u16* A1 = (u16*)alloc((size_t)NA * 256 * 2);
  u16* A2 = (u16*)alloc((size_t)NA * 256 * 2);
  u16* P3 = (u16*)alloc((size_t)NP * 256 * 2);
  float* ldAP_P = (float*)alloc((size_t)NP * 8 * 4);
  float* lsPA_P = (float*)alloc((size_t)NP * 8 * 4);
  float* lsPP_P = (float*)alloc((size_t)NP * 8 * 4);
  float* ldPP_P = (float*)alloc((size_t)NP * 8 * 4);
  float* lsAP_A = (float*)alloc((size_t)NA * 8 * 4);
  float* ldPA_A = (float*)alloc((size_t)NA * 8 * 4);
  u16* wtP0 = (u16*)alloc(256 * 512 * 2);
  u16* wtA0 = (u16*)alloc(256 * 256 * 2);
  u16* wtP1 = (u16*)alloc(256 * 256 * 2);
  u16* wtA1 = (u16*)alloc(256 * 256 * 2);
  u16* kwt0 = (u16*)alloc(256 * 256 * 2);
  u16* kwt1 = (u16*)alloc(256 * 256 * 2);
  u16* lwt = (u16*)alloc(32 * 256 * 2);
  int* rpAP = (int*)alloc((NP + 1) * 4);
  int* rpPP = (int*)alloc((NP + 1) * 4);
  int* rpPA = (int*)alloc((NA + 1) * 4);
  int* eiAP = (int*)alloc((size_t)EAP * 4);
  int* eiPP = (int*)alloc((size_t)EPP * 4);
  int* eiPA = (int*)alloc((size_t)EPA * 4);
  int* bsum = (int*)alloc(768 * 4);
  int* bbase = (int*)alloc(768 * 4);
  size_t zbytes = (size_t)(4 * NP + 2 * NA) * 4 + 4 * 256 * 4;
  char* zblock = alloc(zbytes);
  int* cntAP = (int*)zblock;
  int* cntPP = cntAP + NP;
  int* cntPA = cntPP + NP;
  int* curAP = cntPA + NA;
  int* curPP = curAP + NP;
  int* curPA = curPP + NP;
  float* cs = (float*)(curPA + NA);  // 4 x 256
  float* attnBuf = (float*)alloc(256);

  // Overlay views:
  u16* HP = A1;                       // [NP][256] bf16 spans exactly A1|A2
  u16* hA0 = P2;                      // [NA][256] bf16 = first half of P2
  u16* P2b = P2 + (size_t)NA * 256;   // [NA][256] bf16 = second half of P2 (newA)

  (void)hipMemsetAsync((void*)zblock, 0, zbytes, stream);

  // merged weight transposes (f32 -> bf16)
  k_transpose7<<<CEILDIV(466944, 256), 256, 0, stream>>>(
      W_P[0], wtP0, W_A[0], wtA0, W_P[1], wtP1, W_A[1], wtA1,
      kW[0], kwt0, kW[1], kwt1, linW, lwt);

  // CSR build (by dst), payload = src node id; shared by both layers
  k_hist3<<<CEILDIV(EAP + EPP + EPA, 256), 256, 0, stream>>>(
      dstAP, EAP, cntAP, dstPP, EPP, cntPP, dstPA, EPA, cntPA);
  k_scan_a<<<245, 256, 0, stream>>>(cntAP, cntPP, cntPA, bsum);
  k_scan_b<<<1, 256, 0, stream>>>(bsum, bbase, rpAP, rpPP, rpPA);
  k_scan_c<<<245, 256, 0, stream>>>(cntAP, cntPP, cntPA, bbase, rpAP, rpPP, rpPA);
  k_scatter3<<<CEILDIV(EAP + EPP + EPA, 256), 256, 0, stream>>>(
      dstAP, srcAP, EAP, rpAP, curAP, eiAP,
      dstPP, srcPP, EPP, rpPP, curPP, eiPP,
      dstPA, srcPA, EPA, rpPA, curPA, eiPA);

  int gP = CEILDIV(NP, G3_BM), gA = CEILDIV(NA, G3_BM);
  int bP = CEILDIV(NP, 4), bA = CEILDIV(NA, 4);

  // =================== Layer 0 ===================
  // projections (fused f32->bf16 convert + fused per-head logits)
  k_gemm3<2, 0, 4, 0><<<gP, 512, 0, stream>>>(
      xP, nullptr, nullptr, wtP0, b_P[0], HP, nullptr, NP, 512,
      adAP[0], asPA[0], asPP[0], adPP[0], ldAP_P, lsPA_P, lsPP_P, ldPP_P);
  k_gemm3<2, 0, 2, 0><<<gA, 512, 0, stream>>>(
      xA, nullptr, nullptr, wtA0, b_A[0], hA0, nullptr, NA, 256,
      asAP[0], adPA[0], nullptr, nullptr, lsAP_A, ldPA_A, nullptr, nullptr);

  // merged attn: PP (HP -> P1), PA (HP -> P2b), AP (hA0 -> P3). writes disjoint, race-free.
  k_attn3<<<bP + bA + bP, 256, 0, stream>>>(
      bP, bA,
      rpPP, eiPP, lsPP_P, ldPP_P, HP, P1, NP,
      rpPA, eiPA, lsPA_P, ldPA_A, HP, P2b, NA,
      rpAP, eiAP, lsAP_A, ldAP_P, hA0, P3, NP);

  // merged colsum pair: oAP=P3 -> cs, oPP=P1 -> cs+256
  k_gemm3<0, 1, 0, 1><<<2 * gP, 512, 0, stream>>>(
      P3, P1, nullptr, kwt0, kb[0], nullptr, cs, NP, 256,
      nullptr, nullptr, nullptr, nullptr, nullptr, nullptr, nullptr, nullptr);
  k_scores<<<1, 64, 0, stream>>>(cs, cs + 256, qv[0], 1.0f / NP, attnBuf);

  // fused semantic-combine + layer-1 P projection + layer-1 P logits:
  // hP1 = (a0*P3 + a1*P1) @ W_P1 + b_P1 -> HP
  k_gemm3<1, 0, 4, 0><<<gP, 512, 0, stream>>>(
      P3, P1, attnBuf, wtP1, b_P[1], HP, nullptr, NP, 256,
      adAP[1], asPA[1], asPP[1], adPP[1], ldAP_P, lsPA_P, lsPP_P, ldPP_P);

  // =================== Layer 1 ===================
  k_gemm3<0, 0, 2, 0><<<gA, 512, 0, stream>>>(
      P2b, nullptr, nullptr, wtA1, b_A[1], hA0, nullptr, NA, 256,
      asAP[1], adPA[1], nullptr, nullptr, lsAP_A, ldPA_A, nullptr, nullptr);

  // merged attn: PP (HP -> P1), AP (hA0 -> P3)
  k_attn3<<<bP + bP, 256, 0, stream>>>(
      bP, bP,
      rpPP, eiPP, lsPP_P, ldPP_P, HP, P1, NP,
      rpAP, eiAP, lsAP_A, ldAP_P, hA0, P3, NP,
      nullptr, nullptr, nullptr, nullptr, nullptr, nullptr, 0);

  // merged colsum pair: oAP1=P3 -> cs+512, oPP1=P1 -> cs+768
  k_gemm3<0, 1, 0, 1><<<2 * gP, 512, 0, stream>>>(
      P3, P1, nullptr, kwt1, kb[1], nullptr, cs + 512, NP, 256,
      nullptr, nullptr, nullptr, nullptr, nullptr, nullptr, nullptr, nullptr);
  k_scores<<<1, 64, 0, stream>>>(cs + 512, cs + 768, qv[1], 1.0f / NP, attnBuf + 2);

  // classifier fused with semantic combine: d_out = (a0*P3 + a1*P1) @ linW + linb
  k_gemm2_cls<<<CEILDIV(NP, BM), 256, 0, stream>>>(
      P3, P1, attnBuf + 2, lwt, linb, (float*)d_out, NP, 32, 256);
}